// Round 5
// baseline (427.217 us; speedup 1.0000x reference)
//
#include <hip/hip_runtime.h>
#include <hip/hip_bf16.h>

#define N_NODES 50000
#define N_EDGES 800000
#define IN_CH 256
#define HID 256
#define OUT_CH 128
#define N_GRAPHS 64
#define SCAN_BLOCKS 196     // ceil(50001/256)
#define M_PAD 50048         // 391 * 128
#define COUNT_BLOCKS 3125   // N_EDGES / 256
#define CVTX_BLOCKS  12512  // M_PAD*64 / 256
#define GEMM1_BLOCKS 782    // 391 * 2
#define SROW 50048          // S row stride (f32)
#define S_QUARTER 12512     // SROW / 4 (50 KB LDS slice)
#define GEMM2_BLOCKS 391
#define SBUILD_BLOCKS 256   // 64 graphs * 4 quarters
#define T2_BLOCKS 391       // 50048 / 128
#define T2_KC 128
#define RED_BLOCKS 128      // 8192 outputs / 64
#define AGG_HALF 25024      // M_PAD / 2 (two nodes per thread)
#define AGG_CHUNKS 98       // ceil(25024/256)
#define AGG_BLOCKS (8 * AGG_CHUNKS)   // 8 channel slices (one per XCD)

typedef __bf16 bf16x8 __attribute__((ext_vector_type(8)));
typedef float f32x4 __attribute__((ext_vector_type(4)));
typedef float f32x2 __attribute__((ext_vector_type(2)));
typedef unsigned short u16x8 __attribute__((ext_vector_type(8)));

// bf16 <-> f32 helpers (RNE on pack)
__device__ __forceinline__ float bf2f(unsigned short u) {
    union { unsigned int i; float f; } x; x.i = ((unsigned int)u) << 16; return x.f;
}
__device__ __forceinline__ unsigned short f2bf(float f) {
    union { float f; unsigned int i; } x; x.f = f;
    unsigned int r = x.i + 0x7FFFu + ((x.i >> 16) & 1u);
    return (unsigned short)(r >> 16);
}

// packed bf16x2 (as uint) -> 2 floats: 1 shift + 1 and
__device__ __forceinline__ float lo_f(unsigned int u) {
    return __uint_as_float(u << 16);
}
__device__ __forceinline__ float hi_f(unsigned int u) {
    return __uint_as_float(u & 0xFFFF0000u);
}

__device__ __forceinline__ void load16(const void* g, void* l) {
    __builtin_amdgcn_global_load_lds(
        (const __attribute__((address_space(1))) void*)g,
        (__attribute__((address_space(3))) void*)l, 16, 0, 0);
}

// final rowptr = block-local exclusive + per-256-chunk offset
__device__ __forceinline__ int rp(const int* __restrict__ rl,
                                  const int* __restrict__ boff, int i) {
    return rl[i] + boff[i >> 8];
}

// ---------------------------------------------------------------------------
// Launch A: histogram of dst WITH per-edge rank recording (blocks 0..3124)
// + x f32->bf16 padded convert (blocks 3125..15636). The atomic's return
// value gives each edge its slot within its dst row -> fill needs no atomics.
// ---------------------------------------------------------------------------
__global__ __launch_bounds__(256) void count_cvtx_kernel(const int* __restrict__ ei,
                                                         int* __restrict__ cnt,
                                                         int* __restrict__ erank,
                                                         const float* __restrict__ x,
                                                         unsigned short* __restrict__ xb) {
    int b = blockIdx.x;
    if (b < COUNT_BLOCKS) {
        int e = b * 256 + threadIdx.x;
        erank[e] = atomicAdd(&cnt[ei[N_EDGES + e]], 1);
        return;
    }
    int i = (b - COUNT_BLOCKS) * 256 + threadIdx.x;    // float4 index
    ushort4 o;
    if (i < N_NODES * (IN_CH / 4)) {
        float4 v = ((const float4*)x)[i];
        o.x = f2bf(v.x); o.y = f2bf(v.y); o.z = f2bf(v.z); o.w = f2bf(v.w);
    } else {
        o = make_ushort4(0, 0, 0, 0);
    }
    ((ushort4*)xb)[i] = o;
}

// ---------------------------------------------------------------------------
// scan_a: block-local exclusive scan; emits dinv/invdeg;
// also graph boundary detection (batch sorted) -> rstart[0..64].
// ---------------------------------------------------------------------------
__global__ __launch_bounds__(256) void scan_a_kernel(const int* __restrict__ cnt,
                                                     int* __restrict__ rl,
                                                     int* __restrict__ blocksum,
                                                     float* __restrict__ dinv,
                                                     float* __restrict__ invdeg,
                                                     const int* __restrict__ batch,
                                                     int* __restrict__ rstart) {
    __shared__ int tmp[256];
    int t = threadIdx.x;
    int i = blockIdx.x * 256 + t;
    int v = (i < N_NODES) ? cnt[i] : 0;
    int x = v;
    tmp[t] = x;
    __syncthreads();
    if (i < N_NODES) {
        int bg = batch[i];
        int bp = (i > 0) ? batch[i - 1] : -1;
        for (int g = bp + 1; g <= bg; g++) rstart[g] = i;   // boundary (rare)
        if (i == N_NODES - 1)
            for (int g = bg + 1; g <= N_GRAPHS; g++) rstart[g] = N_NODES;
    }
#pragma unroll
    for (int off = 1; off < 256; off <<= 1) {
        int y = (t >= off) ? tmp[t - off] : 0;
        __syncthreads();
        x += y;
        tmp[t] = x;
        __syncthreads();
    }
    if (i <= N_NODES) rl[i] = x - v;
    if (i < N_NODES) {
        float d = (float)v + 1.0f;         // +1 self loop
        dinv[i] = rsqrtf(d);
        invdeg[i] = 1.0f / d;
    }
    if (t == 255) blocksum[blockIdx.x] = x;
}

// ---------------------------------------------------------------------------
// blocks 0..383: W1/W2 f32 -> bf16 transposed [N][K].
// block 384: scan of block sums -> blockoff.
// ---------------------------------------------------------------------------
__global__ __launch_bounds__(256) void scanb_cvtw_kernel(
        const int* __restrict__ blocksum, int* __restrict__ blockoff,
        const float* __restrict__ W1, const float* __restrict__ W2,
        unsigned short* __restrict__ w1t, unsigned short* __restrict__ w2t) {
    int t = threadIdx.x;
    if (blockIdx.x < 384) {
        int i = blockIdx.x * 256 + t;                 // 0 .. 98303
        if (i < HID * IN_CH) {                        // W1t[n][k] = W1[k][n]
            int n = i >> 8, k = i & 255;
            w1t[i] = f2bf(W1[k * HID + n]);
        } else {                                      // W2t[n][k] = W2[k][n]
            int j = i - HID * IN_CH;
            int n = j >> 8, k = j & 255;
            w2t[j] = f2bf(W2[k * OUT_CH + n]);
        }
        return;
    }
    __shared__ int tmp[256];
    int v = (t < SCAN_BLOCKS) ? blocksum[t] : 0;
    int x = v;
    tmp[t] = x;
    __syncthreads();
#pragma unroll
    for (int off = 1; off < 256; off <<= 1) {
        int y = (t >= off) ? tmp[t - off] : 0;
        __syncthreads();
        x += y;
        tmp[t] = x;
        __syncthreads();
    }
    if (t < SCAN_BLOCKS) blockoff[t] = x - v;
}

// ---------------------------------------------------------------------------
// GEMM tile body (128x128, 4 waves 2x2, 4x4 mfma_f32_16x16x32_bf16,
// global_load_lds width=16 staging, XOR-swizzled LDS chunks).
// TR==0: C[row][col] (row-major, stride N). TR==1: transposed packed store
// h2t[col][row] (stride M_PAD, ushort4 over 4 consecutive rows).
// ---------------------------------------------------------------------------
template <int TR>
__device__ __forceinline__ void gemm_body(const unsigned short* __restrict__ A,
                                          const unsigned short* __restrict__ Bt,
                                          unsigned short* __restrict__ C,
                                          int N, int bxx, int byy, char* As, char* Bs) {
    const int K = 256;
    int tid = threadIdx.x;
    int bm = bxx * 128;
    int bn = byy * 128;
    int lane = tid & 63, wave = tid >> 6;
    int lane15 = lane & 15, quad = lane >> 4;
    int wm0 = (wave >> 1) << 6;
    int wn0 = (wave & 1) << 6;

    int s1 = tid, s2 = tid + 256;
    int r1 = s1 >> 2, q1 = (s1 & 3) ^ ((r1 >> 1) & 3);
    int r2 = s2 >> 2, q2 = (s2 & 3) ^ ((r2 >> 1) & 3);
    const char* gA1 = (const char*)(A + (size_t)(bm + r1) * K) + (q1 << 4);
    const char* gA2 = (const char*)(A + (size_t)(bm + r2) * K) + (q2 << 4);
    const char* gB1 = (const char*)(Bt + (size_t)(bn + r1) * K) + (q1 << 4);
    const char* gB2 = (const char*)(Bt + (size_t)(bn + r2) * K) + (q2 << 4);
    char* lA1 = As + (wave << 10);
    char* lA2 = As + 4096 + (wave << 10);
    char* lB1 = Bs + (wave << 10);
    char* lB2 = Bs + 4096 + (wave << 10);

    int swm = (lane15 >> 1) & 3;
    f32x4 acc[4][4];
#pragma unroll
    for (int mt = 0; mt < 4; mt++)
#pragma unroll
        for (int nt = 0; nt < 4; nt++)
            acc[mt][nt] = (f32x4){0.f, 0.f, 0.f, 0.f};

    for (int k0 = 0; k0 < K; k0 += 32) {
        __syncthreads();
        load16(gA1 + (k0 << 1), lA1);
        load16(gA2 + (k0 << 1), lA2);
        load16(gB1 + (k0 << 1), lB1);
        load16(gB2 + (k0 << 1), lB2);
        __syncthreads();
        bf16x8 af[4], bfr[4];
#pragma unroll
        for (int t = 0; t < 4; t++) {
            int ra = wm0 + t * 16 + lane15;
            af[t] = *(const bf16x8*)(As + ra * 64 + ((quad ^ swm) << 4));
            int rb = wn0 + t * 16 + lane15;
            bfr[t] = *(const bf16x8*)(Bs + rb * 64 + ((quad ^ swm) << 4));
        }
#pragma unroll
        for (int mt = 0; mt < 4; mt++)
#pragma unroll
            for (int nt = 0; nt < 4; nt++)
                acc[mt][nt] = __builtin_amdgcn_mfma_f32_16x16x32_bf16(
                    af[mt], bfr[nt], acc[mt][nt], 0, 0, 0);
    }

#pragma unroll
    for (int mt = 0; mt < 4; mt++) {
        int rowb = bm + wm0 + mt * 16 + quad * 4;
#pragma unroll
        for (int nt = 0; nt < 4; nt++) {
            int col = bn + wn0 + nt * 16 + lane15;
            f32x4 a = acc[mt][nt];
            if (TR == 0) {
                C[(size_t)(rowb + 0) * N + col] = f2bf(a[0]);
                C[(size_t)(rowb + 1) * N + col] = f2bf(a[1]);
                C[(size_t)(rowb + 2) * N + col] = f2bf(a[2]);
                C[(size_t)(rowb + 3) * N + col] = f2bf(a[3]);
            } else {
                ushort4 o;
                o.x = f2bf(a[0]); o.y = f2bf(a[1]);
                o.z = f2bf(a[2]); o.w = f2bf(a[3]);
                *(ushort4*)(C + (size_t)col * M_PAD + rowb) = o;
            }
        }
    }
}

// Launch B: gemm1 tiles (blocks 0..781) + CSR fill (rest, ATOMIC-FREE via
// precomputed ranks); both depend only on the scans.
__global__ __launch_bounds__(256) void fill_gemm1_kernel(
        const int* __restrict__ ei,
        const int* __restrict__ rl,
        const int* __restrict__ boff,
        const int* __restrict__ erank,
        int2* __restrict__ edge2,
        const float* __restrict__ dinv,
        const unsigned short* __restrict__ xb,
        const unsigned short* __restrict__ w1t,
        unsigned short* __restrict__ h1b) {
    __shared__ char As[8192];
    __shared__ char Bs[8192];
    int b = blockIdx.x;
    if (b < GEMM1_BLOCKS) {
        gemm_body<0>(xb, w1t, h1b, HID, b % 391, b / 391, As, Bs);
        return;
    }
    int e = (b - GEMM1_BLOCKS) * 256 + threadIdx.x;
    if (e >= N_EDGES) return;
    int s = ei[e];
    int d = ei[N_EDGES + e];
    int p = rp(rl, boff, d) + erank[e];
    float w = dinv[s] * dinv[d];
    edge2[p] = make_int2(s, __float_as_int(w));
}

// ---------------------------------------------------------------------------
// GCN aggregation conv1, XCD channel-sliced: block b -> channel slice
// (b & 7) * 32 (round-robin dispatch puts all blocks of a slice on one XCD,
// whose 3.2 MB h1b slice then stays L2-resident). Thread = dst node (two
// nodes per thread: n and n+25024, damping degree imbalance). Per edge: one
// 64B line gather (4x dwordx4), 32-ch f32 accumulate, ELU, packed bf16 out.
// Pad rows (50000..50047) zeroed for the t2 path.
// ---------------------------------------------------------------------------
#define EXP2(Q, I, W) \
    acc[I]     += (f32x2){lo_f(Q.x), hi_f(Q.x)} * W; \
    acc[I + 1] += (f32x2){lo_f(Q.y), hi_f(Q.y)} * W; \
    acc[I + 2] += (f32x2){lo_f(Q.z), hi_f(Q.z)} * W; \
    acc[I + 3] += (f32x2){lo_f(Q.w), hi_f(Q.w)} * W;

__global__ __launch_bounds__(256) void agg1_kernel(const unsigned short* __restrict__ h,
                                                   const float* __restrict__ bias,
                                                   const int* __restrict__ rl,
                                                   const int* __restrict__ boff,
                                                   const int2* __restrict__ edge2,
                                                   const float* __restrict__ invdeg,
                                                   unsigned short* __restrict__ out) {
    int cs = (blockIdx.x & 7) * 32;          // channel slice base (per-XCD)
    int na = (blockIdx.x >> 3) * 256 + threadIdx.x;
    if (na >= AGG_HALF) return;
    for (int hh = 0; hh < 2; hh++) {
        int node = na + hh * AGG_HALF;
        uint4* op = (uint4*)(out + (size_t)node * 256 + cs);
        if (node >= N_NODES) {               // pad rows: zero-fill
            uint4 z = make_uint4(0, 0, 0, 0);
            op[0] = z; op[1] = z; op[2] = z; op[3] = z;
            continue;
        }
        f32x2 acc[16];
        const uint4* sp = (const uint4*)(h + (size_t)node * 256 + cs);
        uint4 s0 = sp[0], s1 = sp[1], s2 = sp[2], s3 = sp[3];
        float id = invdeg[node];
#pragma unroll
        for (int i = 0; i < 16; i++) acc[i] = (f32x2){0.f, 0.f};
        EXP2(s0, 0, id); EXP2(s1, 4, id); EXP2(s2, 8, id); EXP2(s3, 12, id);
        int e0 = rp(rl, boff, node);
        int e1 = rp(rl, boff, node + 1);
        int e = e0;
        for (; e + 1 < e1; e += 2) {
            int2 edA = edge2[e], edB = edge2[e + 1];
            const uint4* pA = (const uint4*)(h + (size_t)edA.x * 256 + cs);
            const uint4* pB = (const uint4*)(h + (size_t)edB.x * 256 + cs);
            uint4 a0 = pA[0], a1 = pA[1], a2 = pA[2], a3 = pA[3];
            uint4 b0 = pB[0], b1 = pB[1], b2 = pB[2], b3 = pB[3];
            float wA = __int_as_float(edA.y);
            float wB = __int_as_float(edB.y);
            EXP2(a0, 0, wA); EXP2(a1, 4, wA); EXP2(a2, 8, wA); EXP2(a3, 12, wA);
            EXP2(b0, 0, wB); EXP2(b1, 4, wB); EXP2(b2, 8, wB); EXP2(b3, 12, wB);
        }
        if (e < e1) {
            int2 ed = edge2[e];
            const uint4* p = (const uint4*)(h + (size_t)ed.x * 256 + cs);
            uint4 a0 = p[0], a1 = p[1], a2 = p[2], a3 = p[3];
            float w = __int_as_float(ed.y);
            EXP2(a0, 0, w); EXP2(a1, 4, w); EXP2(a2, 8, w); EXP2(a3, 12, w);
        }
        const f32x2* bp = (const f32x2*)(bias + cs);   // block-uniform: s_loads
        unsigned int ou[16];
#pragma unroll
        for (int i = 0; i < 16; i++) {
            f32x2 a = acc[i] + bp[i];
            a[0] = a[0] > 0.f ? a[0] : expm1f(a[0]);
            a[1] = a[1] > 0.f ? a[1] : expm1f(a[1]);
            ou[i] = (unsigned int)f2bf(a[0]) | ((unsigned int)f2bf(a[1]) << 16);
        }
        op[0] = make_uint4(ou[0], ou[1], ou[2], ou[3]);
        op[1] = make_uint4(ou[4], ou[5], ou[6], ou[7]);
        op[2] = make_uint4(ou[8], ou[9], ou[10], ou[11]);
        op[3] = make_uint4(ou[12], ou[13], ou[14], ou[15]);
    }
}

// ---------------------------------------------------------------------------
// Merged launch: gemm2 tiles (blocks 0..390, h2t transposed output) +
// S-build (blocks 391..646): one block per (graph, column-quarter).
// S[g,s] = invc[g] * (sum_{edges s->d, d in g} w  +  [s in g] * invdeg[s]).
// batch sorted => graph g's CSR edge range is contiguous => block scans it
// with LDS f32 atomics (50 KB slice), zero global atomics, streaming write.
// ---------------------------------------------------------------------------
__global__ __launch_bounds__(256) void gemm2_sbuild_kernel(
        const unsigned short* __restrict__ A,
        const unsigned short* __restrict__ Bt,
        unsigned short* __restrict__ C,
        const int2* __restrict__ edge2,
        const int* __restrict__ rl,
        const int* __restrict__ boff,
        const int* __restrict__ rstart,
        const float* __restrict__ invdeg,
        float* __restrict__ Sp) {
    __shared__ float srow[S_QUARTER];          // 50048 B; gemm uses first 16 KB
    int b = blockIdx.x;
    if (b < GEMM2_BLOCKS) {
        gemm_body<1>(A, Bt, C, OUT_CH, b, 0, (char*)srow, (char*)srow + 8192);
        return;
    }
    int sb = b - GEMM2_BLOCKS;
    int g = sb >> 2;
    int base = (sb & 3) * S_QUARTER;
    int t = threadIdx.x;
    for (int i = t; i < S_QUARTER; i += 256) srow[i] = 0.f;
    int n0 = rstart[g], n1 = rstart[g + 1];
    __syncthreads();
    int e0 = rp(rl, boff, n0);
    int e1 = rp(rl, boff, n1);
    for (int e = e0 + t; e < e1; e += 256) {
        int2 ed = edge2[e];
        unsigned int s = (unsigned int)(ed.x - base);
        if (s < S_QUARTER)
            atomicAdd(&srow[s], __int_as_float(ed.y));
    }
    __syncthreads();
    float ic = 1.0f / fmaxf((float)(n1 - n0), 1.0f);
    float* Sg = Sp + (size_t)g * SROW + base;
    for (int i = t; i < S_QUARTER; i += 256) {
        float v = srow[i];
        int col = base + i;
        if (col >= n0 && col < n1) v += invdeg[col];   // self-loop term
        Sg[i] = v * ic;
    }
}

// ---------------------------------------------------------------------------
// t2 = S @ h2 : [64 x 50048] x [50048 x 128] MFMA GEMM, K-split over 391
// blocks (Kc=128). A = S (f32, split in-kernel into bf16 hi+lo limbs, two
// MFMAs sharing the B fragment -> ~2^-17 weight error, f32 accumulate).
// B = h2t (k-contiguous rows). Pure streaming: no gathers, no LDS.
// ---------------------------------------------------------------------------
__global__ __launch_bounds__(256) void t2_kernel(const float* __restrict__ Sp,
                                                 const unsigned short* __restrict__ h2t,
                                                 float* __restrict__ part) {
    int b = blockIdx.x;
    int k0 = b * T2_KC;
    int tid = threadIdx.x;
    int lane = tid & 63, wave = tid >> 6;
    int lane15 = lane & 15, quad = lane >> 4;
    int cb = wave << 5;                    // 32 channels per wave
    f32x4 acc[4][2];
#pragma unroll
    for (int m = 0; m < 4; m++) {
        acc[m][0] = (f32x4){0.f, 0.f, 0.f, 0.f};
        acc[m][1] = (f32x4){0.f, 0.f, 0.f, 0.f};
    }
    const unsigned short* hr0 = h2t + (size_t)(cb + lane15) * M_PAD;
    const unsigned short* hr1 = h2t + (size_t)(cb + 16 + lane15) * M_PAD;
#pragma unroll
    for (int ks = 0; ks < T2_KC / 32; ks++) {
        int k = k0 + ks * 32 + quad * 8;
        bf16x8 b0 = *(const bf16x8*)(hr0 + k);
        bf16x8 b1 = *(const bf16x8*)(hr1 + k);
#pragma unroll
        for (int m = 0; m < 4; m++) {
            const float* ap = Sp + (size_t)(m * 16 + lane15) * SROW + k;
            f32x4 v0 = *(const f32x4*)ap;
            f32x4 v1 = *(const f32x4*)(ap + 4);
            u16x8 hu, lu;
#pragma unroll
            for (int j = 0; j < 4; j++) {
                unsigned int e0 = __float_as_uint(v0[j]);
                hu[j] = (unsigned short)(e0 >> 16);                       // trunc hi
                lu[j] = f2bf(v0[j] - __uint_as_float(e0 & 0xFFFF0000u));  // residual
                unsigned int e1 = __float_as_uint(v1[j]);
                hu[j + 4] = (unsigned short)(e1 >> 16);
                lu[j + 4] = f2bf(v1[j] - __uint_as_float(e1 & 0xFFFF0000u));
            }
            bf16x8 ah = __builtin_bit_cast(bf16x8, hu);
            bf16x8 al = __builtin_bit_cast(bf16x8, lu);
            acc[m][0] = __builtin_amdgcn_mfma_f32_16x16x32_bf16(ah, b0, acc[m][0], 0, 0, 0);
            acc[m][0] = __builtin_amdgcn_mfma_f32_16x16x32_bf16(al, b0, acc[m][0], 0, 0, 0);
            acc[m][1] = __builtin_amdgcn_mfma_f32_16x16x32_bf16(ah, b1, acc[m][1], 0, 0, 0);
            acc[m][1] = __builtin_amdgcn_mfma_f32_16x16x32_bf16(al, b1, acc[m][1], 0, 0, 0);
        }
    }
    float* pb = part + (size_t)b * (N_GRAPHS * OUT_CH);
#pragma unroll
    for (int m = 0; m < 4; m++) {
        int g0 = m * 16 + quad * 4;
#pragma unroll
        for (int nt = 0; nt < 2; nt++) {
            int c = cb + nt * 16 + lane15;
            f32x4 a = acc[m][nt];
#pragma unroll
            for (int j = 0; j < 4; j++)
                pb[(g0 + j) * OUT_CH + c] = a[j];
        }
    }
}

// reduce partials over 391 blocks, add bias, empty-graph guard, write out.
__global__ __launch_bounds__(256) void t2red_kernel(const float* __restrict__ part,
                                                    const float* __restrict__ b2,
                                                    const int* __restrict__ rstart,
                                                    float* __restrict__ out) {
    __shared__ float red[4][64];
    int tid = threadIdx.x;
    int q = tid >> 6, l = tid & 63;
    int o = blockIdx.x * 64 + l;
    float s = 0.f;
    for (int i = q; i < T2_BLOCKS; i += 4)
        s += part[(size_t)i * (N_GRAPHS * OUT_CH) + o];
    red[q][l] = s;
    __syncthreads();
    if (tid < 64) {
        float tot = red[0][l] + red[1][l] + red[2][l] + red[3][l];
        int g = o >> 7, c = o & 127;
        out[o] = (rstart[g + 1] > rstart[g]) ? tot + b2[c] : 0.f;
    }
}

// ---------------------------------------------------------------------------
extern "C" void kernel_launch(void* const* d_in, const int* in_sizes, int n_in,
                              void* d_out, int out_size, void* d_ws, size_t ws_size,
                              hipStream_t stream) {
    const float* x  = (const float*)d_in[0];
    const float* W1 = (const float*)d_in[1];
    const float* b1 = (const float*)d_in[2];
    const float* W2 = (const float*)d_in[3];
    const float* b2 = (const float*)d_in[4];
    const int*   ei = (const int*)d_in[5];
    const int*   batch = (const int*)d_in[6];
    float* out = (float*)d_out;

    // workspace layout (16B-aligned by construction)
    unsigned short* xb  = (unsigned short*)d_ws;                 // M_PAD*256 bf16
    unsigned short* h1b = xb  + (size_t)M_PAD * IN_CH;           // M_PAD*256 bf16
    unsigned short* hBb = h1b + (size_t)M_PAD * HID;             // M_PAD*256 bf16
    unsigned short* h2t = hBb + (size_t)M_PAD * HID;             // 128*M_PAD bf16 (transposed)
    unsigned short* w1t = h2t + (size_t)OUT_CH * M_PAD;          // 256*256
    unsigned short* w2t = w1t + HID * IN_CH;                     // 128*256
    float* dinv   = (float*)(w2t + OUT_CH * HID);                // 50000
    float* invdeg = dinv + N_NODES;                              // 50000
    int*   rl     = (int*)(invdeg + N_NODES);                    // 50001 (pad 50016)
    int2*  edge2  = (int2*)(rl + 50016);                         // 800000 int2
    int*   cnt    = (int*)(edge2 + N_EDGES);                     // 50000 (memset)
    int*   erank  = cnt + N_NODES;                               // 800000 (edge ranks)
    int*   blocksum = erank + N_EDGES;                           // 256
    int*   blockoff = blocksum + 256;                            // 256
    int*   rstart   = blockoff + 256;                            // 65 (pad 80)
    float* Sp     = (float*)(rstart + 80);                       // 64*50048 f32
    float* part   = (float*)xb;   // t2 partials alias xb (dead after gemm1)

    hipMemsetAsync(cnt, 0, (size_t)N_NODES * 4, stream);

    // A: histogram+rank + x convert (independent, one launch)
    count_cvtx_kernel<<<COUNT_BLOCKS + CVTX_BLOCKS, 256, 0, stream>>>(ei, cnt, erank, x, xb);
    // scan phase (detects graph boundaries)
    scan_a_kernel<<<SCAN_BLOCKS, 256, 0, stream>>>(cnt, rl, blocksum, dinv, invdeg,
                                                   batch, rstart);
    // weight convert + blocksum scan
    scanb_cvtw_kernel<<<385, 256, 0, stream>>>(blocksum, blockoff, W1, W2, w1t, w2t);
    // B: gemm1 tiles + atomic-free CSR fill (one launch)
    fill_gemm1_kernel<<<GEMM1_BLOCKS + COUNT_BLOCKS, 256, 0, stream>>>(
        ei, rl, blockoff, erank, edge2, dinv, xb, w1t, h1b);
    // conv1 aggregate (+ELU), XCD channel-sliced; pads zeroed for t2 path
    agg1_kernel<<<AGG_BLOCKS, 256, 0, stream>>>(h1b, b1, rl, blockoff,
                                                edge2, invdeg, hBb);
    // conv2 GEMM (h2t transposed out) + S-build (LDS, no global atomics)
    gemm2_sbuild_kernel<<<GEMM2_BLOCKS + SBUILD_BLOCKS, 256, 0, stream>>>(
        hBb, w2t, h2t, edge2, rl, blockoff, rstart, invdeg, Sp);
    // fused agg2+pool+mean as dense streaming GEMM out = S @ h2 + b2
    t2_kernel<<<T2_BLOCKS, 256, 0, stream>>>(Sp, h2t, part);
    t2red_kernel<<<RED_BLOCKS, 256, 0, stream>>>(part, b2, rstart, out);
}

// Round 6
// 330.420 us; speedup vs baseline: 1.2930x; 1.2930x over previous
//
#include <hip/hip_runtime.h>
#include <hip/hip_bf16.h>

#define N_NODES 50000
#define N_EDGES 800000
#define IN_CH 256
#define HID 256
#define OUT_CH 128
#define N_GRAPHS 64
#define SCAN_BLOCKS 196     // ceil(50001/256)
#define M_PAD 50048         // 391 * 128
#define COUNT_BLOCKS 3125   // N_EDGES / 256
#define CVTX_BLOCKS  12512  // M_PAD*64 / 256
#define GEMM1_BLOCKS 782    // 391 * 2
#define SROW 50048          // S row stride (f32)
#define S_QUARTER 12512     // SROW / 4 (50 KB LDS slice)
#define GEMM2_BLOCKS 391
#define SBUILD_BLOCKS 256   // 64 graphs * 4 quarters
#define T2_BLOCKS 391       // 50048 / 128
#define T2_KC 128
#define RED_BLOCKS 128      // 8192 outputs / 64
#define AGG1_BLOCKS 6256    // 8 slices * (M_PAD/64 = 782) node-chunks

typedef __bf16 bf16x8 __attribute__((ext_vector_type(8)));
typedef float f32x4 __attribute__((ext_vector_type(4)));
typedef float f32x2 __attribute__((ext_vector_type(2)));
typedef unsigned short u16x8 __attribute__((ext_vector_type(8)));

// bf16 <-> f32 helpers (RNE on pack)
__device__ __forceinline__ float bf2f(unsigned short u) {
    union { unsigned int i; float f; } x; x.i = ((unsigned int)u) << 16; return x.f;
}
__device__ __forceinline__ unsigned short f2bf(float f) {
    union { float f; unsigned int i; } x; x.f = f;
    unsigned int r = x.i + 0x7FFFu + ((x.i >> 16) & 1u);
    return (unsigned short)(r >> 16);
}

// packed bf16x2 (as uint) -> 2 floats: 1 shift + 1 and
__device__ __forceinline__ float lo_f(unsigned int u) {
    return __uint_as_float(u << 16);
}
__device__ __forceinline__ float hi_f(unsigned int u) {
    return __uint_as_float(u & 0xFFFF0000u);
}

// non-temporal 8B load of an edge record (keeps edge stream out of hot L2)
__device__ __forceinline__ int2 nt_edge(const int2* p) {
    long long v = __builtin_nontemporal_load((const long long*)p);
    int2 r;
    r.x = (int)(v & 0xFFFFFFFFll);
    r.y = (int)(v >> 32);
    return r;
}

__device__ __forceinline__ void load16(const void* g, void* l) {
    __builtin_amdgcn_global_load_lds(
        (const __attribute__((address_space(1))) void*)g,
        (__attribute__((address_space(3))) void*)l, 16, 0, 0);
}

// final rowptr = block-local exclusive + per-256-chunk offset
__device__ __forceinline__ int rp(const int* __restrict__ rl,
                                  const int* __restrict__ boff, int i) {
    return rl[i] + boff[i >> 8];
}

// ---------------------------------------------------------------------------
// Launch A: histogram of dst WITH per-edge rank recording (blocks 0..3124)
// + x f32->bf16 padded convert (blocks 3125..15636). The atomic's return
// value gives each edge its slot within its dst row -> fill needs no atomics.
// ---------------------------------------------------------------------------
__global__ __launch_bounds__(256) void count_cvtx_kernel(const int* __restrict__ ei,
                                                         int* __restrict__ cnt,
                                                         int* __restrict__ erank,
                                                         const float* __restrict__ x,
                                                         unsigned short* __restrict__ xb) {
    int b = blockIdx.x;
    if (b < COUNT_BLOCKS) {
        int e = b * 256 + threadIdx.x;
        erank[e] = atomicAdd(&cnt[ei[N_EDGES + e]], 1);
        return;
    }
    int i = (b - COUNT_BLOCKS) * 256 + threadIdx.x;    // float4 index
    ushort4 o;
    if (i < N_NODES * (IN_CH / 4)) {
        float4 v = ((const float4*)x)[i];
        o.x = f2bf(v.x); o.y = f2bf(v.y); o.z = f2bf(v.z); o.w = f2bf(v.w);
    } else {
        o = make_ushort4(0, 0, 0, 0);
    }
    ((ushort4*)xb)[i] = o;
}

// ---------------------------------------------------------------------------
// scan_a: block-local exclusive scan; emits dinv/invdeg;
// also graph boundary detection (batch sorted) -> rstart[0..64].
// ---------------------------------------------------------------------------
__global__ __launch_bounds__(256) void scan_a_kernel(const int* __restrict__ cnt,
                                                     int* __restrict__ rl,
                                                     int* __restrict__ blocksum,
                                                     float* __restrict__ dinv,
                                                     float* __restrict__ invdeg,
                                                     const int* __restrict__ batch,
                                                     int* __restrict__ rstart) {
    __shared__ int tmp[256];
    int t = threadIdx.x;
    int i = blockIdx.x * 256 + t;
    int v = (i < N_NODES) ? cnt[i] : 0;
    int x = v;
    tmp[t] = x;
    __syncthreads();
    if (i < N_NODES) {
        int bg = batch[i];
        int bp = (i > 0) ? batch[i - 1] : -1;
        for (int g = bp + 1; g <= bg; g++) rstart[g] = i;   // boundary (rare)
        if (i == N_NODES - 1)
            for (int g = bg + 1; g <= N_GRAPHS; g++) rstart[g] = N_NODES;
    }
#pragma unroll
    for (int off = 1; off < 256; off <<= 1) {
        int y = (t >= off) ? tmp[t - off] : 0;
        __syncthreads();
        x += y;
        tmp[t] = x;
        __syncthreads();
    }
    if (i <= N_NODES) rl[i] = x - v;
    if (i < N_NODES) {
        float d = (float)v + 1.0f;         // +1 self loop
        dinv[i] = rsqrtf(d);
        invdeg[i] = 1.0f / d;
    }
    if (t == 255) blocksum[blockIdx.x] = x;
}

// ---------------------------------------------------------------------------
// blocks 0..383: W1/W2 f32 -> bf16 transposed [N][K].
// block 384: scan of block sums -> blockoff.
// ---------------------------------------------------------------------------
__global__ __launch_bounds__(256) void scanb_cvtw_kernel(
        const int* __restrict__ blocksum, int* __restrict__ blockoff,
        const float* __restrict__ W1, const float* __restrict__ W2,
        unsigned short* __restrict__ w1t, unsigned short* __restrict__ w2t) {
    int t = threadIdx.x;
    if (blockIdx.x < 384) {
        int i = blockIdx.x * 256 + t;                 // 0 .. 98303
        if (i < HID * IN_CH) {                        // W1t[n][k] = W1[k][n]
            int n = i >> 8, k = i & 255;
            w1t[i] = f2bf(W1[k * HID + n]);
        } else {                                      // W2t[n][k] = W2[k][n]
            int j = i - HID * IN_CH;
            int n = j >> 8, k = j & 255;
            w2t[j] = f2bf(W2[k * OUT_CH + n]);
        }
        return;
    }
    __shared__ int tmp[256];
    int v = (t < SCAN_BLOCKS) ? blocksum[t] : 0;
    int x = v;
    tmp[t] = x;
    __syncthreads();
#pragma unroll
    for (int off = 1; off < 256; off <<= 1) {
        int y = (t >= off) ? tmp[t - off] : 0;
        __syncthreads();
        x += y;
        tmp[t] = x;
        __syncthreads();
    }
    if (t < SCAN_BLOCKS) blockoff[t] = x - v;
}

// ---------------------------------------------------------------------------
// GEMM tile body (128x128, 4 waves 2x2, 4x4 mfma_f32_16x16x32_bf16,
// global_load_lds width=16 staging, XOR-swizzled LDS chunks).
// TR==0: C[row][col] (row-major, stride N).
// TR==1: transposed packed store h2t[col][row] (stride M_PAD, ushort4).
// TR==2: slice-major store h1s[col>>5][row][col&31] (32-ch slices, 64B rows)
//        so a channel-slice is a contiguous 3.2MB block (L2-resident/XCD).
// ---------------------------------------------------------------------------
template <int TR>
__device__ __forceinline__ void gemm_body(const unsigned short* __restrict__ A,
                                          const unsigned short* __restrict__ Bt,
                                          unsigned short* __restrict__ C,
                                          int N, int bxx, int byy, char* As, char* Bs) {
    const int K = 256;
    int tid = threadIdx.x;
    int bm = bxx * 128;
    int bn = byy * 128;
    int lane = tid & 63, wave = tid >> 6;
    int lane15 = lane & 15, quad = lane >> 4;
    int wm0 = (wave >> 1) << 6;
    int wn0 = (wave & 1) << 6;

    int s1 = tid, s2 = tid + 256;
    int r1 = s1 >> 2, q1 = (s1 & 3) ^ ((r1 >> 1) & 3);
    int r2 = s2 >> 2, q2 = (s2 & 3) ^ ((r2 >> 1) & 3);
    const char* gA1 = (const char*)(A + (size_t)(bm + r1) * K) + (q1 << 4);
    const char* gA2 = (const char*)(A + (size_t)(bm + r2) * K) + (q2 << 4);
    const char* gB1 = (const char*)(Bt + (size_t)(bn + r1) * K) + (q1 << 4);
    const char* gB2 = (const char*)(Bt + (size_t)(bn + r2) * K) + (q2 << 4);
    char* lA1 = As + (wave << 10);
    char* lA2 = As + 4096 + (wave << 10);
    char* lB1 = Bs + (wave << 10);
    char* lB2 = Bs + 4096 + (wave << 10);

    int swm = (lane15 >> 1) & 3;
    f32x4 acc[4][4];
#pragma unroll
    for (int mt = 0; mt < 4; mt++)
#pragma unroll
        for (int nt = 0; nt < 4; nt++)
            acc[mt][nt] = (f32x4){0.f, 0.f, 0.f, 0.f};

    for (int k0 = 0; k0 < K; k0 += 32) {
        __syncthreads();
        load16(gA1 + (k0 << 1), lA1);
        load16(gA2 + (k0 << 1), lA2);
        load16(gB1 + (k0 << 1), lB1);
        load16(gB2 + (k0 << 1), lB2);
        __syncthreads();
        bf16x8 af[4], bfr[4];
#pragma unroll
        for (int t = 0; t < 4; t++) {
            int ra = wm0 + t * 16 + lane15;
            af[t] = *(const bf16x8*)(As + ra * 64 + ((quad ^ swm) << 4));
            int rb = wn0 + t * 16 + lane15;
            bfr[t] = *(const bf16x8*)(Bs + rb * 64 + ((quad ^ swm) << 4));
        }
#pragma unroll
        for (int mt = 0; mt < 4; mt++)
#pragma unroll
            for (int nt = 0; nt < 4; nt++)
                acc[mt][nt] = __builtin_amdgcn_mfma_f32_16x16x32_bf16(
                    af[mt], bfr[nt], acc[mt][nt], 0, 0, 0);
    }

#pragma unroll
    for (int mt = 0; mt < 4; mt++) {
        int rowb = bm + wm0 + mt * 16 + quad * 4;
#pragma unroll
        for (int nt = 0; nt < 4; nt++) {
            int col = bn + wn0 + nt * 16 + lane15;
            f32x4 a = acc[mt][nt];
            if (TR == 0) {
                C[(size_t)(rowb + 0) * N + col] = f2bf(a[0]);
                C[(size_t)(rowb + 1) * N + col] = f2bf(a[1]);
                C[(size_t)(rowb + 2) * N + col] = f2bf(a[2]);
                C[(size_t)(rowb + 3) * N + col] = f2bf(a[3]);
            } else if (TR == 1) {
                ushort4 o;
                o.x = f2bf(a[0]); o.y = f2bf(a[1]);
                o.z = f2bf(a[2]); o.w = f2bf(a[3]);
                *(ushort4*)(C + (size_t)col * M_PAD + rowb) = o;
            } else {
                unsigned short* base =
                    C + ((size_t)(col >> 5) * M_PAD + rowb) * 32 + (col & 31);
                base[0]  = f2bf(a[0]);
                base[32] = f2bf(a[1]);
                base[64] = f2bf(a[2]);
                base[96] = f2bf(a[3]);
            }
        }
    }
}

// Launch B: gemm1 tiles (blocks 0..781, slice-major h1s output) + CSR fill
// (rest, ATOMIC-FREE via precomputed ranks); both depend only on the scans.
__global__ __launch_bounds__(256) void fill_gemm1_kernel(
        const int* __restrict__ ei,
        const int* __restrict__ rl,
        const int* __restrict__ boff,
        const int* __restrict__ erank,
        int2* __restrict__ edge2,
        const float* __restrict__ dinv,
        const unsigned short* __restrict__ xb,
        const unsigned short* __restrict__ w1t,
        unsigned short* __restrict__ h1b) {
    __shared__ char As[8192];
    __shared__ char Bs[8192];
    int b = blockIdx.x;
    if (b < GEMM1_BLOCKS) {
        gemm_body<2>(xb, w1t, h1b, HID, b % 391, b / 391, As, Bs);
        return;
    }
    int e = (b - GEMM1_BLOCKS) * 256 + threadIdx.x;
    if (e >= N_EDGES) return;
    int s = ei[e];
    int d = ei[N_EDGES + e];
    int p = rp(rl, boff, d) + erank[e];
    float w = dinv[s] * dinv[d];
    edge2[p] = make_int2(s, __float_as_int(w));
}

// ---------------------------------------------------------------------------
// GCN aggregation conv1, XCD-sliced with SLICE-MAJOR input h1s[slice][node][32]:
// block b -> slice (b & 7) (round-robin dispatch pins slice to one XCD whose
// contiguous 3.2MB slice stays L2-resident; no line sharing across slices).
// 16-lane group per node: one fully-used 64B gather per edge (coalesced),
// f32x2 accumulate per lane, ELU, packed bf16 row-major out. Edge records
// loaded non-temporally (8x re-read stream, L3-resident; don't evict slice).
// Pad rows 50000..50047 zero-filled for the t2 path.
// ---------------------------------------------------------------------------
__global__ __launch_bounds__(256) void agg1_kernel(const unsigned short* __restrict__ h,
                                                   const float* __restrict__ bias,
                                                   const int* __restrict__ rl,
                                                   const int* __restrict__ boff,
                                                   const int2* __restrict__ edge2,
                                                   const float* __restrict__ invdeg,
                                                   unsigned short* __restrict__ out) {
    int slice = blockIdx.x & 7;
    int cs = slice * 32;
    const unsigned int* hs = (const unsigned int*)(h + (size_t)slice * M_PAD * 32);
    int grp = threadIdx.x >> 4;        // 0..15 (group of 16 lanes per node)
    int lph = threadIdx.x & 15;        // lane in group: 2 channels (1 uint)
    int nb = (blockIdx.x >> 3) * 64;   // 64 nodes per block
    float2 bb = ((const float2*)(bias + cs))[lph];
#pragma unroll
    for (int it = 0; it < 4; it++) {
        int node = nb + it * 16 + grp;
        unsigned int* op = (unsigned int*)(out + (size_t)node * 256 + cs) + lph;
        if (node >= N_NODES) { *op = 0u; continue; }
        unsigned int svu = hs[node * 16 + lph];
        float id = invdeg[node];
        f32x2 acc = (f32x2){lo_f(svu) * id, hi_f(svu) * id};
        int e0 = rp(rl, boff, node);
        int e1 = rp(rl, boff, node + 1);
        int e = e0;
        for (; e + 7 < e1; e += 8) {
            int2 ed[8];
            unsigned int v[8];
#pragma unroll
            for (int j = 0; j < 8; j++) ed[j] = nt_edge(edge2 + e + j);
#pragma unroll
            for (int j = 0; j < 8; j++) v[j] = hs[(size_t)ed[j].x * 16 + lph];
#pragma unroll
            for (int j = 0; j < 8; j++) {
                float w = __int_as_float(ed[j].y);
                acc += (f32x2){lo_f(v[j]), hi_f(v[j])} * w;
            }
        }
        for (; e + 3 < e1; e += 4) {
            int2 ed[4];
            unsigned int v[4];
#pragma unroll
            for (int j = 0; j < 4; j++) ed[j] = nt_edge(edge2 + e + j);
#pragma unroll
            for (int j = 0; j < 4; j++) v[j] = hs[(size_t)ed[j].x * 16 + lph];
#pragma unroll
            for (int j = 0; j < 4; j++) {
                float w = __int_as_float(ed[j].y);
                acc += (f32x2){lo_f(v[j]), hi_f(v[j])} * w;
            }
        }
        for (; e < e1; e++) {
            int2 ed = nt_edge(edge2 + e);
            unsigned int v = hs[(size_t)ed.x * 16 + lph];
            float w = __int_as_float(ed.y);
            acc += (f32x2){lo_f(v), hi_f(v)} * w;
        }
        float a0 = acc[0] + bb.x;
        float a1 = acc[1] + bb.y;
        a0 = a0 > 0.f ? a0 : expm1f(a0);
        a1 = a1 > 0.f ? a1 : expm1f(a1);
        *op = (unsigned int)f2bf(a0) | ((unsigned int)f2bf(a1) << 16);
    }
}

// ---------------------------------------------------------------------------
// Merged launch: gemm2 tiles (blocks 0..390, h2t transposed output) +
// S-build (blocks 391..646): one block per (graph, column-quarter).
// S[g,s] = invc[g] * (sum_{edges s->d, d in g} w  +  [s in g] * invdeg[s]).
// batch sorted => graph g's CSR edge range is contiguous => block scans it
// with LDS f32 atomics (50 KB slice), zero global atomics, streaming write.
// ---------------------------------------------------------------------------
__global__ __launch_bounds__(256) void gemm2_sbuild_kernel(
        const unsigned short* __restrict__ A,
        const unsigned short* __restrict__ Bt,
        unsigned short* __restrict__ C,
        const int2* __restrict__ edge2,
        const int* __restrict__ rl,
        const int* __restrict__ boff,
        const int* __restrict__ rstart,
        const float* __restrict__ invdeg,
        float* __restrict__ Sp) {
    __shared__ float srow[S_QUARTER];          // 50048 B; gemm uses first 16 KB
    int b = blockIdx.x;
    if (b < GEMM2_BLOCKS) {
        gemm_body<1>(A, Bt, C, OUT_CH, b, 0, (char*)srow, (char*)srow + 8192);
        return;
    }
    int sb = b - GEMM2_BLOCKS;
    int g = sb >> 2;
    int base = (sb & 3) * S_QUARTER;
    int t = threadIdx.x;
    for (int i = t; i < S_QUARTER; i += 256) srow[i] = 0.f;
    int n0 = rstart[g], n1 = rstart[g + 1];
    __syncthreads();
    int e0 = rp(rl, boff, n0);
    int e1 = rp(rl, boff, n1);
    for (int e = e0 + t; e < e1; e += 256) {
        int2 ed = edge2[e];
        unsigned int s = (unsigned int)(ed.x - base);
        if (s < S_QUARTER)
            atomicAdd(&srow[s], __int_as_float(ed.y));
    }
    __syncthreads();
    float ic = 1.0f / fmaxf((float)(n1 - n0), 1.0f);
    float* Sg = Sp + (size_t)g * SROW + base;
    for (int i = t; i < S_QUARTER; i += 256) {
        float v = srow[i];
        int col = base + i;
        if (col >= n0 && col < n1) v += invdeg[col];   // self-loop term
        Sg[i] = v * ic;
    }
}

// ---------------------------------------------------------------------------
// t2 = S @ h2 : [64 x 50048] x [50048 x 128] MFMA GEMM, K-split over 391
// blocks (Kc=128). A = S (f32, split in-kernel into bf16 hi+lo limbs, two
// MFMAs sharing the B fragment -> ~2^-17 weight error, f32 accumulate).
// B = h2t (k-contiguous rows). Pure streaming: no gathers, no LDS.
// ---------------------------------------------------------------------------
__global__ __launch_bounds__(256) void t2_kernel(const float* __restrict__ Sp,
                                                 const unsigned short* __restrict__ h2t,
                                                 float* __restrict__ part) {
    int b = blockIdx.x;
    int k0 = b * T2_KC;
    int tid = threadIdx.x;
    int lane = tid & 63, wave = tid >> 6;
    int lane15 = lane & 15, quad = lane >> 4;
    int cb = wave << 5;                    // 32 channels per wave
    f32x4 acc[4][2];
#pragma unroll
    for (int m = 0; m < 4; m++) {
        acc[m][0] = (f32x4){0.f, 0.f, 0.f, 0.f};
        acc[m][1] = (f32x4){0.f, 0.f, 0.f, 0.f};
    }
    const unsigned short* hr0 = h2t + (size_t)(cb + lane15) * M_PAD;
    const unsigned short* hr1 = h2t + (size_t)(cb + 16 + lane15) * M_PAD;
#pragma unroll
    for (int ks = 0; ks < T2_KC / 32; ks++) {
        int k = k0 + ks * 32 + quad * 8;
        bf16x8 b0 = *(const bf16x8*)(hr0 + k);
        bf16x8 b1 = *(const bf16x8*)(hr1 + k);
#pragma unroll
        for (int m = 0; m < 4; m++) {
            const float* ap = Sp + (size_t)(m * 16 + lane15) * SROW + k;
            f32x4 v0 = *(const f32x4*)ap;
            f32x4 v1 = *(const f32x4*)(ap + 4);
            u16x8 hu, lu;
#pragma unroll
            for (int j = 0; j < 4; j++) {
                unsigned int e0 = __float_as_uint(v0[j]);
                hu[j] = (unsigned short)(e0 >> 16);                       // trunc hi
                lu[j] = f2bf(v0[j] - __uint_as_float(e0 & 0xFFFF0000u));  // residual
                unsigned int e1 = __float_as_uint(v1[j]);
                hu[j + 4] = (unsigned short)(e1 >> 16);
                lu[j + 4] = f2bf(v1[j] - __uint_as_float(e1 & 0xFFFF0000u));
            }
            bf16x8 ah = __builtin_bit_cast(bf16x8, hu);
            bf16x8 al = __builtin_bit_cast(bf16x8, lu);
            acc[m][0] = __builtin_amdgcn_mfma_f32_16x16x32_bf16(ah, b0, acc[m][0], 0, 0, 0);
            acc[m][0] = __builtin_amdgcn_mfma_f32_16x16x32_bf16(al, b0, acc[m][0], 0, 0, 0);
            acc[m][1] = __builtin_amdgcn_mfma_f32_16x16x32_bf16(ah, b1, acc[m][1], 0, 0, 0);
            acc[m][1] = __builtin_amdgcn_mfma_f32_16x16x32_bf16(al, b1, acc[m][1], 0, 0, 0);
        }
    }
    float* pb = part + (size_t)b * (N_GRAPHS * OUT_CH);
#pragma unroll
    for (int m = 0; m < 4; m++) {
        int g0 = m * 16 + quad * 4;
#pragma unroll
        for (int nt = 0; nt < 2; nt++) {
            int c = cb + nt * 16 + lane15;
            f32x4 a = acc[m][nt];
#pragma unroll
            for (int j = 0; j < 4; j++)
                pb[(g0 + j) * OUT_CH + c] = a[j];
        }
    }
}

// reduce partials over 391 blocks, add bias, empty-graph guard, write out.
__global__ __launch_bounds__(256) void t2red_kernel(const float* __restrict__ part,
                                                    const float* __restrict__ b2,
                                                    const int* __restrict__ rstart,
                                                    float* __restrict__ out) {
    __shared__ float red[4][64];
    int tid = threadIdx.x;
    int q = tid >> 6, l = tid & 63;
    int o = blockIdx.x * 64 + l;
    float s = 0.f;
    for (int i = q; i < T2_BLOCKS; i += 4)
        s += part[(size_t)i * (N_GRAPHS * OUT_CH) + o];
    red[q][l] = s;
    __syncthreads();
    if (tid < 64) {
        float tot = red[0][l] + red[1][l] + red[2][l] + red[3][l];
        int g = o >> 7, c = o & 127;
        out[o] = (rstart[g + 1] > rstart[g]) ? tot + b2[c] : 0.f;
    }
}

// ---------------------------------------------------------------------------
extern "C" void kernel_launch(void* const* d_in, const int* in_sizes, int n_in,
                              void* d_out, int out_size, void* d_ws, size_t ws_size,
                              hipStream_t stream) {
    const float* x  = (const float*)d_in[0];
    const float* W1 = (const float*)d_in[1];
    const float* b1 = (const float*)d_in[2];
    const float* W2 = (const float*)d_in[3];
    const float* b2 = (const float*)d_in[4];
    const int*   ei = (const int*)d_in[5];
    const int*   batch = (const int*)d_in[6];
    float* out = (float*)d_out;

    // workspace layout (16B-aligned by construction)
    unsigned short* xb  = (unsigned short*)d_ws;                 // M_PAD*256 bf16
    unsigned short* h1b = xb  + (size_t)M_PAD * IN_CH;           // M_PAD*256 bf16 (slice-major)
    unsigned short* hBb = h1b + (size_t)M_PAD * HID;             // M_PAD*256 bf16
    unsigned short* h2t = hBb + (size_t)M_PAD * HID;             // 128*M_PAD bf16 (transposed)
    unsigned short* w1t = h2t + (size_t)OUT_CH * M_PAD;          // 256*256
    unsigned short* w2t = w1t + HID * IN_CH;                     // 128*256
    float* dinv   = (float*)(w2t + OUT_CH * HID);                // 50000
    float* invdeg = dinv + N_NODES;                              // 50000
    int*   rl     = (int*)(invdeg + N_NODES);                    // 50001 (pad 50016)
    int2*  edge2  = (int2*)(rl + 50016);                         // 800000 int2
    int*   cnt    = (int*)(edge2 + N_EDGES);                     // 50000 (memset)
    int*   erank  = cnt + N_NODES;                               // 800000 (edge ranks)
    int*   blocksum = erank + N_EDGES;                           // 256
    int*   blockoff = blocksum + 256;                            // 256
    int*   rstart   = blockoff + 256;                            // 65 (pad 80)
    float* Sp     = (float*)(rstart + 80);                       // 64*50048 f32
    float* part   = (float*)xb;   // t2 partials alias xb (dead after gemm1)

    hipMemsetAsync(cnt, 0, (size_t)N_NODES * 4, stream);

    // A: histogram+rank + x convert (independent, one launch)
    count_cvtx_kernel<<<COUNT_BLOCKS + CVTX_BLOCKS, 256, 0, stream>>>(ei, cnt, erank, x, xb);
    // scan phase (detects graph boundaries)
    scan_a_kernel<<<SCAN_BLOCKS, 256, 0, stream>>>(cnt, rl, blocksum, dinv, invdeg,
                                                   batch, rstart);
    // weight convert + blocksum scan
    scanb_cvtw_kernel<<<385, 256, 0, stream>>>(blocksum, blockoff, W1, W2, w1t, w2t);
    // B: gemm1 tiles (slice-major out) + atomic-free CSR fill (one launch)
    fill_gemm1_kernel<<<GEMM1_BLOCKS + COUNT_BLOCKS, 256, 0, stream>>>(
        ei, rl, blockoff, erank, edge2, dinv, xb, w1t, h1b);
    // conv1 aggregate (+ELU), XCD slice-resident; pads zeroed for t2 path
    agg1_kernel<<<AGG1_BLOCKS, 256, 0, stream>>>(h1b, b1, rl, blockoff,
                                                 edge2, invdeg, hBb);
    // conv2 GEMM (h2t transposed out) + S-build (LDS, no global atomics)
    gemm2_sbuild_kernel<<<GEMM2_BLOCKS + SBUILD_BLOCKS, 256, 0, stream>>>(
        hBb, w2t, h2t, edge2, rl, blockoff, rstart, invdeg, Sp);
    // fused agg2+pool+mean as dense streaming GEMM out = S @ h2 + b2
    t2_kernel<<<T2_BLOCKS, 256, 0, stream>>>(Sp, h2t, part);
    t2red_kernel<<<RED_BLOCKS, 256, 0, stream>>>(part, b2, rstart, out);
}

// Round 7
// 301.113 us; speedup vs baseline: 1.4188x; 1.0973x over previous
//
#include <hip/hip_runtime.h>
#include <hip/hip_bf16.h>

#define N_NODES 50000
#define N_EDGES 800000
#define IN_CH 256
#define HID 256
#define OUT_CH 128
#define N_GRAPHS 64
#define SCAN_BLOCKS 196     // ceil(50001/256)
#define M_PAD 50048         // 391 * 128
#define COUNT_BLOCKS 3125   // N_EDGES / 256
#define CVTX_BLOCKS  12512  // M_PAD*64 / 256
#define CVTW_BLOCKS  384    // (256*256 + 128*256) / 256
#define GEMM1_BLOCKS 782    // 391 * 2
#define SROW 50048          // S row stride (f32)
#define S_EIGHTH 6256       // SROW / 8 (25 KB LDS slice)
#define SBUILD8_BLOCKS 512  // 64 graphs * 8 eighths
#define GEMM2_BLOCKS 391
#define T2_BLOCKS 391       // 50048 / 128
#define T2_KC 128
#define RED_BLOCKS 128      // 8192 outputs / 64

typedef __bf16 bf16x8 __attribute__((ext_vector_type(8)));
typedef float f32x4 __attribute__((ext_vector_type(4)));
typedef float f32x2 __attribute__((ext_vector_type(2)));
typedef unsigned short u16x8 __attribute__((ext_vector_type(8)));

// bf16 <-> f32 helpers (RNE on pack)
__device__ __forceinline__ float bf2f(unsigned short u) {
    union { unsigned int i; float f; } x; x.i = ((unsigned int)u) << 16; return x.f;
}
__device__ __forceinline__ unsigned short f2bf(float f) {
    union { float f; unsigned int i; } x; x.f = f;
    unsigned int r = x.i + 0x7FFFu + ((x.i >> 16) & 1u);
    return (unsigned short)(r >> 16);
}

// packed bf16x2 (as uint) -> 2 floats: 1 shift + 1 and
__device__ __forceinline__ float lo_f(unsigned int u) {
    return __uint_as_float(u << 16);
}
__device__ __forceinline__ float hi_f(unsigned int u) {
    return __uint_as_float(u & 0xFFFF0000u);
}

__device__ __forceinline__ void load16(const void* g, void* l) {
    __builtin_amdgcn_global_load_lds(
        (const __attribute__((address_space(1))) void*)g,
        (__attribute__((address_space(3))) void*)l, 16, 0, 0);
}

// final rowptr = block-local exclusive + per-256-chunk offset
__device__ __forceinline__ int rp(const int* __restrict__ rl,
                                  const int* __restrict__ boff, int i) {
    return rl[i] + boff[i >> 8];
}

// ---------------------------------------------------------------------------
// Launch A: histogram of dst WITH per-edge rank recording (blocks 0..3124)
// + x f32->bf16 padded convert (next 12512) + W1/W2 f32->bf16 transposed
// convert (last 384). All independent; one dispatch.
// ---------------------------------------------------------------------------
__global__ __launch_bounds__(256) void count_cvtx_cvtw_kernel(
        const int* __restrict__ ei, int* __restrict__ cnt, int* __restrict__ erank,
        const float* __restrict__ x, unsigned short* __restrict__ xb,
        const float* __restrict__ W1, const float* __restrict__ W2,
        unsigned short* __restrict__ w1t, unsigned short* __restrict__ w2t) {
    int b = blockIdx.x;
    if (b < COUNT_BLOCKS) {
        int e = b * 256 + threadIdx.x;
        erank[e] = atomicAdd(&cnt[ei[N_EDGES + e]], 1);
        return;
    }
    b -= COUNT_BLOCKS;
    if (b < CVTX_BLOCKS) {
        int i = b * 256 + threadIdx.x;    // float4 index
        ushort4 o;
        if (i < N_NODES * (IN_CH / 4)) {
            float4 v = ((const float4*)x)[i];
            o.x = f2bf(v.x); o.y = f2bf(v.y); o.z = f2bf(v.z); o.w = f2bf(v.w);
        } else {
            o = make_ushort4(0, 0, 0, 0);
        }
        ((ushort4*)xb)[i] = o;
        return;
    }
    int i = (b - CVTX_BLOCKS) * 256 + threadIdx.x;    // 0 .. 98303
    if (i < HID * IN_CH) {                        // W1t[n][k] = W1[k][n]
        int n = i >> 8, k = i & 255;
        w1t[i] = f2bf(W1[k * HID + n]);
    } else {                                      // W2t[n][k] = W2[k][n]
        int j = i - HID * IN_CH;
        int n = j >> 8, k = j & 255;
        w2t[j] = f2bf(W2[k * OUT_CH + n]);
    }
}

// ---------------------------------------------------------------------------
// scan_a: block-local exclusive scan; emits dinv/invdeg;
// also graph boundary detection (batch sorted) -> rstart[0..64].
// ---------------------------------------------------------------------------
__global__ __launch_bounds__(256) void scan_a_kernel(const int* __restrict__ cnt,
                                                     int* __restrict__ rl,
                                                     int* __restrict__ blocksum,
                                                     float* __restrict__ dinv,
                                                     float* __restrict__ invdeg,
                                                     const int* __restrict__ batch,
                                                     int* __restrict__ rstart) {
    __shared__ int tmp[256];
    int t = threadIdx.x;
    int i = blockIdx.x * 256 + t;
    int v = (i < N_NODES) ? cnt[i] : 0;
    int x = v;
    tmp[t] = x;
    __syncthreads();
    if (i < N_NODES) {
        int bg = batch[i];
        int bp = (i > 0) ? batch[i - 1] : -1;
        for (int g = bp + 1; g <= bg; g++) rstart[g] = i;   // boundary (rare)
        if (i == N_NODES - 1)
            for (int g = bg + 1; g <= N_GRAPHS; g++) rstart[g] = N_NODES;
    }
#pragma unroll
    for (int off = 1; off < 256; off <<= 1) {
        int y = (t >= off) ? tmp[t - off] : 0;
        __syncthreads();
        x += y;
        tmp[t] = x;
        __syncthreads();
    }
    if (i <= N_NODES) rl[i] = x - v;
    if (i < N_NODES) {
        float d = (float)v + 1.0f;         // +1 self loop
        dinv[i] = rsqrtf(d);
        invdeg[i] = 1.0f / d;
    }
    if (t == 255) blocksum[blockIdx.x] = x;
}

// single block: scan of per-block sums -> blockoff
__global__ __launch_bounds__(256) void scanb1_kernel(const int* __restrict__ blocksum,
                                                     int* __restrict__ blockoff) {
    __shared__ int tmp[256];
    int t = threadIdx.x;
    int v = (t < SCAN_BLOCKS) ? blocksum[t] : 0;
    int x = v;
    tmp[t] = x;
    __syncthreads();
#pragma unroll
    for (int off = 1; off < 256; off <<= 1) {
        int y = (t >= off) ? tmp[t - off] : 0;
        __syncthreads();
        x += y;
        tmp[t] = x;
        __syncthreads();
    }
    if (t < SCAN_BLOCKS) blockoff[t] = x - v;
}

// ---------------------------------------------------------------------------
// GEMM tile body (128x128, 4 waves 2x2, 4x4 mfma_f32_16x16x32_bf16,
// global_load_lds width=16 staging, XOR-swizzled LDS chunks).
// TR==0: C[row][col] (row-major, stride N). TR==1: transposed packed store
// h2t[col][row] (stride M_PAD, ushort4 over 4 consecutive rows).
// ---------------------------------------------------------------------------
template <int TR>
__device__ __forceinline__ void gemm_body(const unsigned short* __restrict__ A,
                                          const unsigned short* __restrict__ Bt,
                                          unsigned short* __restrict__ C,
                                          int N, int bxx, int byy, char* As, char* Bs) {
    const int K = 256;
    int tid = threadIdx.x;
    int bm = bxx * 128;
    int bn = byy * 128;
    int lane = tid & 63, wave = tid >> 6;
    int lane15 = lane & 15, quad = lane >> 4;
    int wm0 = (wave >> 1) << 6;
    int wn0 = (wave & 1) << 6;

    int s1 = tid, s2 = tid + 256;
    int r1 = s1 >> 2, q1 = (s1 & 3) ^ ((r1 >> 1) & 3);
    int r2 = s2 >> 2, q2 = (s2 & 3) ^ ((r2 >> 1) & 3);
    const char* gA1 = (const char*)(A + (size_t)(bm + r1) * K) + (q1 << 4);
    const char* gA2 = (const char*)(A + (size_t)(bm + r2) * K) + (q2 << 4);
    const char* gB1 = (const char*)(Bt + (size_t)(bn + r1) * K) + (q1 << 4);
    const char* gB2 = (const char*)(Bt + (size_t)(bn + r2) * K) + (q2 << 4);
    char* lA1 = As + (wave << 10);
    char* lA2 = As + 4096 + (wave << 10);
    char* lB1 = Bs + (wave << 10);
    char* lB2 = Bs + 4096 + (wave << 10);

    int swm = (lane15 >> 1) & 3;
    f32x4 acc[4][4];
#pragma unroll
    for (int mt = 0; mt < 4; mt++)
#pragma unroll
        for (int nt = 0; nt < 4; nt++)
            acc[mt][nt] = (f32x4){0.f, 0.f, 0.f, 0.f};

    for (int k0 = 0; k0 < K; k0 += 32) {
        __syncthreads();
        load16(gA1 + (k0 << 1), lA1);
        load16(gA2 + (k0 << 1), lA2);
        load16(gB1 + (k0 << 1), lB1);
        load16(gB2 + (k0 << 1), lB2);
        __syncthreads();
        bf16x8 af[4], bfr[4];
#pragma unroll
        for (int t = 0; t < 4; t++) {
            int ra = wm0 + t * 16 + lane15;
            af[t] = *(const bf16x8*)(As + ra * 64 + ((quad ^ swm) << 4));
            int rb = wn0 + t * 16 + lane15;
            bfr[t] = *(const bf16x8*)(Bs + rb * 64 + ((quad ^ swm) << 4));
        }
#pragma unroll
        for (int mt = 0; mt < 4; mt++)
#pragma unroll
            for (int nt = 0; nt < 4; nt++)
                acc[mt][nt] = __builtin_amdgcn_mfma_f32_16x16x32_bf16(
                    af[mt], bfr[nt], acc[mt][nt], 0, 0, 0);
    }

#pragma unroll
    for (int mt = 0; mt < 4; mt++) {
        int rowb = bm + wm0 + mt * 16 + quad * 4;
#pragma unroll
        for (int nt = 0; nt < 4; nt++) {
            int col = bn + wn0 + nt * 16 + lane15;
            f32x4 a = acc[mt][nt];
            if (TR == 0) {
                C[(size_t)(rowb + 0) * N + col] = f2bf(a[0]);
                C[(size_t)(rowb + 1) * N + col] = f2bf(a[1]);
                C[(size_t)(rowb + 2) * N + col] = f2bf(a[2]);
                C[(size_t)(rowb + 3) * N + col] = f2bf(a[3]);
            } else {
                ushort4 o;
                o.x = f2bf(a[0]); o.y = f2bf(a[1]);
                o.z = f2bf(a[2]); o.w = f2bf(a[3]);
                *(ushort4*)(C + (size_t)col * M_PAD + rowb) = o;
            }
        }
    }
}

// Launch B: gemm1 tiles (blocks 0..781, row-major h1b) + CSR fill (rest,
// ATOMIC-FREE via precomputed ranks); both depend only on the scans.
__global__ __launch_bounds__(256) void fill_gemm1_kernel(
        const int* __restrict__ ei,
        const int* __restrict__ rl,
        const int* __restrict__ boff,
        const int* __restrict__ erank,
        int2* __restrict__ edge2,
        const float* __restrict__ dinv,
        const unsigned short* __restrict__ xb,
        const unsigned short* __restrict__ w1t,
        unsigned short* __restrict__ h1b) {
    __shared__ char As[8192];
    __shared__ char Bs[8192];
    int b = blockIdx.x;
    if (b < GEMM1_BLOCKS) {
        gemm_body<0>(xb, w1t, h1b, HID, b % 391, b / 391, As, Bs);
        return;
    }
    int e = (b - GEMM1_BLOCKS) * 256 + threadIdx.x;
    if (e >= N_EDGES) return;
    int s = ei[e];
    int d = ei[N_EDGES + e];
    int p = rp(rl, boff, d) + erank[e];
    float w = dinv[s] * dinv[d];
    edge2[p] = make_int2(s, __float_as_int(w));
}

// ---------------------------------------------------------------------------
// Launch C: S-build eighths (blocks 0..511) + GCN aggregation conv1
// (round-4 proven form: wave/node, lane = 4ch uint2 gathers, 16-edge unroll).
// sbuild placed FIRST so its ~12us hides fully under agg1's ~61us; 25KB LDS
// keeps occupancy at 6 blocks/CU = 24 waves (above agg1's ~19-wave need).
// S[g,s] = (sum_{edges s->d, d in g} w + [s in g]*invdeg[s]) / count(g).
// Pad rows 50000..50047 zero-filled for the t2 path.
// ---------------------------------------------------------------------------
__global__ __launch_bounds__(256) void agg1_sbuild_kernel(
        const unsigned short* __restrict__ h,
        const float* __restrict__ bias,
        const int* __restrict__ rl,
        const int* __restrict__ boff,
        const int2* __restrict__ edge2,
        const float* __restrict__ invdeg,
        unsigned short* __restrict__ out,
        const int* __restrict__ rstart,
        float* __restrict__ Sp) {
    __shared__ float srow[S_EIGHTH];           // 25024 B
    int b = blockIdx.x;
    if (b < SBUILD8_BLOCKS) {
        int g = b >> 3;
        int base = (b & 7) * S_EIGHTH;
        int t = threadIdx.x;
        for (int i = t; i < S_EIGHTH; i += 256) srow[i] = 0.f;
        int n0 = rstart[g], n1 = rstart[g + 1];
        __syncthreads();
        int e0 = rp(rl, boff, n0);
        int e1 = rp(rl, boff, n1);
        for (int e = e0 + t; e < e1; e += 256) {
            int2 ed = edge2[e];
            unsigned int s = (unsigned int)(ed.x - base);
            if (s < S_EIGHTH)
                atomicAdd(&srow[s], __int_as_float(ed.y));
        }
        __syncthreads();
        float ic = 1.0f / fmaxf((float)(n1 - n0), 1.0f);
        float* Sg = Sp + (size_t)g * SROW + base;
        for (int i = t; i < S_EIGHTH; i += 256) {
            float v = srow[i];
            int col = base + i;
            if (col >= n0 && col < n1) v += invdeg[col];   // self-loop term
            Sg[i] = v * ic;
        }
        return;
    }
    int node = (b - SBUILD8_BLOCKS) * 4 + (threadIdx.x >> 6);
    int lane = threadIdx.x & 63;
    if (node >= N_NODES) {
        if (node < M_PAD)
            ((ushort4*)out)[(size_t)node * 64 + lane] = make_ushort4(0, 0, 0, 0);
        return;
    }
    const uint2* h4 = (const uint2*)h;
    float id = invdeg[node];
    uint2 sv = h4[(size_t)node * 64 + lane];
    f32x4 acc = (f32x4){lo_f(sv.x) * id, hi_f(sv.x) * id,
                        lo_f(sv.y) * id, hi_f(sv.y) * id};
    int e0 = rp(rl, boff, node);
    int e1 = rp(rl, boff, node + 1);
    int e = e0;
    for (; e + 15 < e1; e += 16) {
        int2 ed[16];
        uint2 v[16];
#pragma unroll
        for (int j = 0; j < 16; j++) ed[j] = edge2[e + j];
#pragma unroll
        for (int j = 0; j < 16; j++) v[j] = h4[(size_t)ed[j].x * 64 + lane];
#pragma unroll
        for (int j = 0; j < 16; j++) {
            float w = __int_as_float(ed[j].y);
            f32x4 vf = (f32x4){lo_f(v[j].x), hi_f(v[j].x),
                               lo_f(v[j].y), hi_f(v[j].y)};
            acc += vf * w;
        }
    }
    for (; e + 7 < e1; e += 8) {
        int2 ed[8];
        uint2 v[8];
#pragma unroll
        for (int j = 0; j < 8; j++) ed[j] = edge2[e + j];
#pragma unroll
        for (int j = 0; j < 8; j++) v[j] = h4[(size_t)ed[j].x * 64 + lane];
#pragma unroll
        for (int j = 0; j < 8; j++) {
            float w = __int_as_float(ed[j].y);
            f32x4 vf = (f32x4){lo_f(v[j].x), hi_f(v[j].x),
                               lo_f(v[j].y), hi_f(v[j].y)};
            acc += vf * w;
        }
    }
    for (; e + 3 < e1; e += 4) {
        int2 ed[4];
        uint2 v[4];
#pragma unroll
        for (int j = 0; j < 4; j++) ed[j] = edge2[e + j];
#pragma unroll
        for (int j = 0; j < 4; j++) v[j] = h4[(size_t)ed[j].x * 64 + lane];
#pragma unroll
        for (int j = 0; j < 4; j++) {
            float w = __int_as_float(ed[j].y);
            f32x4 vf = (f32x4){lo_f(v[j].x), hi_f(v[j].x),
                               lo_f(v[j].y), hi_f(v[j].y)};
            acc += vf * w;
        }
    }
    for (; e < e1; e++) {
        int2 ed0 = edge2[e];
        float w0 = __int_as_float(ed0.y);
        uint2 v0 = h4[(size_t)ed0.x * 64 + lane];
        f32x4 vf = (f32x4){lo_f(v0.x), hi_f(v0.x), lo_f(v0.y), hi_f(v0.y)};
        acc += vf * w0;
    }
    float4 bb = ((const float4*)bias)[lane];
    acc[0] += bb.x; acc[1] += bb.y; acc[2] += bb.z; acc[3] += bb.w;
    acc[0] = acc[0] > 0.f ? acc[0] : expm1f(acc[0]);
    acc[1] = acc[1] > 0.f ? acc[1] : expm1f(acc[1]);
    acc[2] = acc[2] > 0.f ? acc[2] : expm1f(acc[2]);
    acc[3] = acc[3] > 0.f ? acc[3] : expm1f(acc[3]);
    ushort4 o;
    o.x = f2bf(acc[0]); o.y = f2bf(acc[1]); o.z = f2bf(acc[2]); o.w = f2bf(acc[3]);
    ((ushort4*)out)[(size_t)node * 64 + lane] = o;
}

// conv2 GEMM, h2t transposed output (pure, sbuild moved out)
__global__ __launch_bounds__(256) void gemm2_kernel(
        const unsigned short* __restrict__ A,
        const unsigned short* __restrict__ Bt,
        unsigned short* __restrict__ C) {
    __shared__ char As[8192];
    __shared__ char Bs[8192];
    gemm_body<1>(A, Bt, C, OUT_CH, blockIdx.x, 0, As, Bs);
}

// ---------------------------------------------------------------------------
// t2 = S @ h2 : [64 x 50048] x [50048 x 128] MFMA GEMM, K-split over 391
// blocks (Kc=128). A = S (f32, split in-kernel into bf16 hi+lo limbs, two
// MFMAs sharing the B fragment -> ~2^-17 weight error, f32 accumulate).
// B = h2t (k-contiguous rows). Pure streaming: no gathers, no LDS.
// ---------------------------------------------------------------------------
__global__ __launch_bounds__(256) void t2_kernel(const float* __restrict__ Sp,
                                                 const unsigned short* __restrict__ h2t,
                                                 float* __restrict__ part) {
    int b = blockIdx.x;
    int k0 = b * T2_KC;
    int tid = threadIdx.x;
    int lane = tid & 63, wave = tid >> 6;
    int lane15 = lane & 15, quad = lane >> 4;
    int cb = wave << 5;                    // 32 channels per wave
    f32x4 acc[4][2];
#pragma unroll
    for (int m = 0; m < 4; m++) {
        acc[m][0] = (f32x4){0.f, 0.f, 0.f, 0.f};
        acc[m][1] = (f32x4){0.f, 0.f, 0.f, 0.f};
    }
    const unsigned short* hr0 = h2t + (size_t)(cb + lane15) * M_PAD;
    const unsigned short* hr1 = h2t + (size_t)(cb + 16 + lane15) * M_PAD;
#pragma unroll
    for (int ks = 0; ks < T2_KC / 32; ks++) {
        int k = k0 + ks * 32 + quad * 8;
        bf16x8 b0 = *(const bf16x8*)(hr0 + k);
        bf16x8 b1 = *(const bf16x8*)(hr1 + k);
#pragma unroll
        for (int m = 0; m < 4; m++) {
            const float* ap = Sp + (size_t)(m * 16 + lane15) * SROW + k;
            f32x4 v0 = *(const f32x4*)ap;
            f32x4 v1 = *(const f32x4*)(ap + 4);
            u16x8 hu, lu;
#pragma unroll
            for (int j = 0; j < 4; j++) {
                unsigned int e0 = __float_as_uint(v0[j]);
                hu[j] = (unsigned short)(e0 >> 16);                       // trunc hi
                lu[j] = f2bf(v0[j] - __uint_as_float(e0 & 0xFFFF0000u));  // residual
                unsigned int e1 = __float_as_uint(v1[j]);
                hu[j + 4] = (unsigned short)(e1 >> 16);
                lu[j + 4] = f2bf(v1[j] - __uint_as_float(e1 & 0xFFFF0000u));
            }
            bf16x8 ah = __builtin_bit_cast(bf16x8, hu);
            bf16x8 al = __builtin_bit_cast(bf16x8, lu);
            acc[m][0] = __builtin_amdgcn_mfma_f32_16x16x32_bf16(ah, b0, acc[m][0], 0, 0, 0);
            acc[m][0] = __builtin_amdgcn_mfma_f32_16x16x32_bf16(al, b0, acc[m][0], 0, 0, 0);
            acc[m][1] = __builtin_amdgcn_mfma_f32_16x16x32_bf16(ah, b1, acc[m][1], 0, 0, 0);
            acc[m][1] = __builtin_amdgcn_mfma_f32_16x16x32_bf16(al, b1, acc[m][1], 0, 0, 0);
        }
    }
    float* pb = part + (size_t)b * (N_GRAPHS * OUT_CH);
#pragma unroll
    for (int m = 0; m < 4; m++) {
        int g0 = m * 16 + quad * 4;
#pragma unroll
        for (int nt = 0; nt < 2; nt++) {
            int c = cb + nt * 16 + lane15;
            f32x4 a = acc[m][nt];
#pragma unroll
            for (int j = 0; j < 4; j++)
                pb[(g0 + j) * OUT_CH + c] = a[j];
        }
    }
}

// reduce partials over 391 blocks, add bias, empty-graph guard, write out.
__global__ __launch_bounds__(256) void t2red_kernel(const float* __restrict__ part,
                                                    const float* __restrict__ b2,
                                                    const int* __restrict__ rstart,
                                                    float* __restrict__ out) {
    __shared__ float red[4][64];
    int tid = threadIdx.x;
    int q = tid >> 6, l = tid & 63;
    int o = blockIdx.x * 64 + l;
    float s = 0.f;
    for (int i = q; i < T2_BLOCKS; i += 4)
        s += part[(size_t)i * (N_GRAPHS * OUT_CH) + o];
    red[q][l] = s;
    __syncthreads();
    if (tid < 64) {
        float tot = red[0][l] + red[1][l] + red[2][l] + red[3][l];
        int g = o >> 7, c = o & 127;
        out[o] = (rstart[g + 1] > rstart[g]) ? tot + b2[c] : 0.f;
    }
}

// ---------------------------------------------------------------------------
extern "C" void kernel_launch(void* const* d_in, const int* in_sizes, int n_in,
                              void* d_out, int out_size, void* d_ws, size_t ws_size,
                              hipStream_t stream) {
    const float* x  = (const float*)d_in[0];
    const float* W1 = (const float*)d_in[1];
    const float* b1 = (const float*)d_in[2];
    const float* W2 = (const float*)d_in[3];
    const float* b2 = (const float*)d_in[4];
    const int*   ei = (const int*)d_in[5];
    const int*   batch = (const int*)d_in[6];
    float* out = (float*)d_out;

    // workspace layout (16B-aligned by construction)
    unsigned short* xb  = (unsigned short*)d_ws;                 // M_PAD*256 bf16
    unsigned short* h1b = xb  + (size_t)M_PAD * IN_CH;           // M_PAD*256 bf16
    unsigned short* hBb = h1b + (size_t)M_PAD * HID;             // M_PAD*256 bf16
    unsigned short* h2t = hBb + (size_t)M_PAD * HID;             // 128*M_PAD bf16 (transposed)
    unsigned short* w1t = h2t + (size_t)OUT_CH * M_PAD;          // 256*256
    unsigned short* w2t = w1t + HID * IN_CH;                     // 128*256
    float* dinv   = (float*)(w2t + OUT_CH * HID);                // 50000
    float* invdeg = dinv + N_NODES;                              // 50000
    int*   rl     = (int*)(invdeg + N_NODES);                    // 50001 (pad 50016)
    int2*  edge2  = (int2*)(rl + 50016);                         // 800000 int2
    int*   cnt    = (int*)(edge2 + N_EDGES);                     // 50000 (memset)
    int*   erank  = cnt + N_NODES;                               // 800000 (edge ranks)
    int*   blocksum = erank + N_EDGES;                           // 256
    int*   blockoff = blocksum + 256;                            // 256
    int*   rstart   = blockoff + 256;                            // 65 (pad 80)
    float* Sp     = (float*)(rstart + 80);                       // 64*50048 f32
    float* part   = (float*)xb;   // t2 partials alias xb (dead after gemm1)

    hipMemsetAsync(cnt, 0, (size_t)N_NODES * 4, stream);

    // A: histogram+rank + x convert + W convert (independent, one launch)
    count_cvtx_cvtw_kernel<<<COUNT_BLOCKS + CVTX_BLOCKS + CVTW_BLOCKS, 256, 0, stream>>>(
        ei, cnt, erank, x, xb, W1, W2, w1t, w2t);
    // scan phase (detects graph boundaries)
    scan_a_kernel<<<SCAN_BLOCKS, 256, 0, stream>>>(cnt, rl, blocksum, dinv, invdeg,
                                                   batch, rstart);
    // blockoff scan (single block)
    scanb1_kernel<<<1, 256, 0, stream>>>(blocksum, blockoff);
    // B: gemm1 tiles + atomic-free CSR fill (one launch)
    fill_gemm1_kernel<<<GEMM1_BLOCKS + COUNT_BLOCKS, 256, 0, stream>>>(
        ei, rl, blockoff, erank, edge2, dinv, xb, w1t, h1b);
    // C: S-build (eighths, first) + conv1 aggregate (+ELU, round-4 form)
    agg1_sbuild_kernel<<<SBUILD8_BLOCKS + M_PAD / 4, 256, 0, stream>>>(
        h1b, b1, rl, blockoff, edge2, invdeg, hBb, rstart, Sp);
    // conv2 GEMM (h2t transposed out)
    gemm2_kernel<<<GEMM2_BLOCKS, 256, 0, stream>>>(hBb, w2t, h2t);
    // fused agg2+pool+mean as dense streaming GEMM out = S @ h2 + b2
    t2_kernel<<<T2_BLOCKS, 256, 0, stream>>>(Sp, h2t, part);
    t2red_kernel<<<RED_BLOCKS, 256, 0, stream>>>(part, b2, rstart, out);
}

// Round 9
// 300.638 us; speedup vs baseline: 1.4210x; 1.0016x over previous
//
#include <hip/hip_runtime.h>
#include <hip/hip_bf16.h>

#define N_NODES 50000
#define N_EDGES 800000
#define IN_CH 256
#define HID 256
#define OUT_CH 128
#define N_GRAPHS 64
#define SCAN_BLOCKS 196     // ceil(50001/256)
#define M_PAD 50048         // 391 * 128
#define COUNT_BLOCKS 3125   // N_EDGES / 256
#define CVTX_BLOCKS  12512  // M_PAD*64 / 256
#define CVTW_BLOCKS  384    // (256*256 + 128*256) / 256
#define GEMM1_BLOCKS 782    // 391 * 2
#define SROW 50048          // S row stride (f32)
#define S_QUARTER 12512     // SROW / 4 (50 KB LDS slice)
#define GEMM2_BLOCKS 391
#define SBUILD_BLOCKS 256   // 64 graphs * 4 quarters
#define T2_BLOCKS 391       // 50048 / 128
#define T2_KC 128
#define RED_BLOCKS 128      // 8192 outputs / 64

typedef __bf16 bf16x8 __attribute__((ext_vector_type(8)));
typedef float f32x4 __attribute__((ext_vector_type(4)));
typedef unsigned short u16x8 __attribute__((ext_vector_type(8)));

// bf16 <-> f32 helpers (RNE on pack)
__device__ __forceinline__ float bf2f(unsigned short u) {
    union { unsigned int i; float f; } x; x.i = ((unsigned int)u) << 16; return x.f;
}
__device__ __forceinline__ unsigned short f2bf(float f) {
    union { float f; unsigned int i; } x; x.f = f;
    unsigned int r = x.i + 0x7FFFu + ((x.i >> 16) & 1u);
    return (unsigned short)(r >> 16);
}

// packed bf16x2 (as uint) -> 2 floats: 1 shift + 1 and
__device__ __forceinline__ float lo_f(unsigned int u) {
    return __uint_as_float(u << 16);
}
__device__ __forceinline__ float hi_f(unsigned int u) {
    return __uint_as_float(u & 0xFFFF0000u);
}

__device__ __forceinline__ void load16(const void* g, void* l) {
    __builtin_amdgcn_global_load_lds(
        (const __attribute__((address_space(1))) void*)g,
        (__attribute__((address_space(3))) void*)l, 16, 0, 0);
}

// final rowptr = block-local exclusive + per-256-chunk offset
__device__ __forceinline__ int rp(const int* __restrict__ rl,
                                  const int* __restrict__ boff, int i) {
    return rl[i] + boff[i >> 8];
}

// ---------------------------------------------------------------------------
// Launch A: histogram of dst WITH per-edge rank recording (blocks 0..3124)
// + x f32->bf16 padded convert (next 12512) + W1/W2 f32->bf16 transposed
// convert (last 384). All independent; one dispatch.
// ---------------------------------------------------------------------------
__global__ __launch_bounds__(256) void count_cvtx_cvtw_kernel(
        const int* __restrict__ ei, int* __restrict__ cnt, int* __restrict__ erank,
        const float* __restrict__ x, unsigned short* __restrict__ xb,
        const float* __restrict__ W1, const float* __restrict__ W2,
        unsigned short* __restrict__ w1t, unsigned short* __restrict__ w2t) {
    int b = blockIdx.x;
    if (b < COUNT_BLOCKS) {
        int e = b * 256 + threadIdx.x;
        erank[e] = atomicAdd(&cnt[ei[N_EDGES + e]], 1);
        return;
    }
    b -= COUNT_BLOCKS;
    if (b < CVTX_BLOCKS) {
        int i = b * 256 + threadIdx.x;    // float4 index
        ushort4 o;
        if (i < N_NODES * (IN_CH / 4)) {
            float4 v = ((const float4*)x)[i];
            o.x = f2bf(v.x); o.y = f2bf(v.y); o.z = f2bf(v.z); o.w = f2bf(v.w);
        } else {
            o = make_ushort4(0, 0, 0, 0);
        }
        ((ushort4*)xb)[i] = o;
        return;
    }
    int i = (b - CVTX_BLOCKS) * 256 + threadIdx.x;    // 0 .. 98303
    if (i < HID * IN_CH) {                        // W1t[n][k] = W1[k][n]
        int n = i >> 8, k = i & 255;
        w1t[i] = f2bf(W1[k * HID + n]);
    } else {                                      // W2t[n][k] = W2[k][n]
        int j = i - HID * IN_CH;
        int n = j >> 8, k = j & 255;
        w2t[j] = f2bf(W2[k * OUT_CH + n]);
    }
}

// ---------------------------------------------------------------------------
// scan_a: block-local exclusive scan; emits dinv/invdeg;
// also graph boundary detection (batch sorted) -> rstart[0..64].
// ---------------------------------------------------------------------------
__global__ __launch_bounds__(256) void scan_a_kernel(const int* __restrict__ cnt,
                                                     int* __restrict__ rl,
                                                     int* __restrict__ blocksum,
                                                     float* __restrict__ dinv,
                                                     float* __restrict__ invdeg,
                                                     const int* __restrict__ batch,
                                                     int* __restrict__ rstart) {
    __shared__ int tmp[256];
    int t = threadIdx.x;
    int i = blockIdx.x * 256 + t;
    int v = (i < N_NODES) ? cnt[i] : 0;
    int x = v;
    tmp[t] = x;
    __syncthreads();
    if (i < N_NODES) {
        int bg = batch[i];
        int bp = (i > 0) ? batch[i - 1] : -1;
        for (int g = bp + 1; g <= bg; g++) rstart[g] = i;   // boundary (rare)
        if (i == N_NODES - 1)
            for (int g = bg + 1; g <= N_GRAPHS; g++) rstart[g] = N_NODES;
    }
#pragma unroll
    for (int off = 1; off < 256; off <<= 1) {
        int y = (t >= off) ? tmp[t - off] : 0;
        __syncthreads();
        x += y;
        tmp[t] = x;
        __syncthreads();
    }
    if (i <= N_NODES) rl[i] = x - v;
    if (i < N_NODES) {
        float d = (float)v + 1.0f;         // +1 self loop
        dinv[i] = rsqrtf(d);
        invdeg[i] = 1.0f / d;
    }
    if (t == 255) blocksum[blockIdx.x] = x;
}

// single block: scan of per-block sums -> blockoff
__global__ __launch_bounds__(256) void scanb1_kernel(const int* __restrict__ blocksum,
                                                     int* __restrict__ blockoff) {
    __shared__ int tmp[256];
    int t = threadIdx.x;
    int v = (t < SCAN_BLOCKS) ? blocksum[t] : 0;
    int x = v;
    tmp[t] = x;
    __syncthreads();
#pragma unroll
    for (int off = 1; off < 256; off <<= 1) {
        int y = (t >= off) ? tmp[t - off] : 0;
        __syncthreads();
        x += y;
        tmp[t] = x;
        __syncthreads();
    }
    if (t < SCAN_BLOCKS) blockoff[t] = x - v;
}

// ---------------------------------------------------------------------------
// GEMM tile body (128x128, 4 waves 2x2, 4x4 mfma_f32_16x16x32_bf16,
// global_load_lds width=16 staging, XOR-swizzled LDS chunks).
// TR==0: C[row][col] (row-major, stride N). TR==1: transposed packed store
// h2t[col][row] (stride M_PAD, ushort4 over 4 consecutive rows).
// ---------------------------------------------------------------------------
template <int TR>
__device__ __forceinline__ void gemm_body(const unsigned short* __restrict__ A,
                                          const unsigned short* __restrict__ Bt,
                                          unsigned short* __restrict__ C,
                                          int N, int bxx, int byy, char* As, char* Bs) {
    const int K = 256;
    int tid = threadIdx.x;
    int bm = bxx * 128;
    int bn = byy * 128;
    int lane = tid & 63, wave = tid >> 6;
    int lane15 = lane & 15, quad = lane >> 4;
    int wm0 = (wave >> 1) << 6;
    int wn0 = (wave & 1) << 6;

    int s1 = tid, s2 = tid + 256;
    int r1 = s1 >> 2, q1 = (s1 & 3) ^ ((r1 >> 1) & 3);
    int r2 = s2 >> 2, q2 = (s2 & 3) ^ ((r2 >> 1) & 3);
    const char* gA1 = (const char*)(A + (size_t)(bm + r1) * K) + (q1 << 4);
    const char* gA2 = (const char*)(A + (size_t)(bm + r2) * K) + (q2 << 4);
    const char* gB1 = (const char*)(Bt + (size_t)(bn + r1) * K) + (q1 << 4);
    const char* gB2 = (const char*)(Bt + (size_t)(bn + r2) * K) + (q2 << 4);
    char* lA1 = As + (wave << 10);
    char* lA2 = As + 4096 + (wave << 10);
    char* lB1 = Bs + (wave << 10);
    char* lB2 = Bs + 4096 + (wave << 10);

    int swm = (lane15 >> 1) & 3;
    f32x4 acc[4][4];
#pragma unroll
    for (int mt = 0; mt < 4; mt++)
#pragma unroll
        for (int nt = 0; nt < 4; nt++)
            acc[mt][nt] = (f32x4){0.f, 0.f, 0.f, 0.f};

    for (int k0 = 0; k0 < K; k0 += 32) {
        __syncthreads();
        load16(gA1 + (k0 << 1), lA1);
        load16(gA2 + (k0 << 1), lA2);
        load16(gB1 + (k0 << 1), lB1);
        load16(gB2 + (k0 << 1), lB2);
        __syncthreads();
        bf16x8 af[4], bfr[4];
#pragma unroll
        for (int t = 0; t < 4; t++) {
            int ra = wm0 + t * 16 + lane15;
            af[t] = *(const bf16x8*)(As + ra * 64 + ((quad ^ swm) << 4));
            int rb = wn0 + t * 16 + lane15;
            bfr[t] = *(const bf16x8*)(Bs + rb * 64 + ((quad ^ swm) << 4));
        }
#pragma unroll
        for (int mt = 0; mt < 4; mt++)
#pragma unroll
            for (int nt = 0; nt < 4; nt++)
                acc[mt][nt] = __builtin_amdgcn_mfma_f32_16x16x32_bf16(
                    af[mt], bfr[nt], acc[mt][nt], 0, 0, 0);
    }

#pragma unroll
    for (int mt = 0; mt < 4; mt++) {
        int rowb = bm + wm0 + mt * 16 + quad * 4;
#pragma unroll
        for (int nt = 0; nt < 4; nt++) {
            int col = bn + wn0 + nt * 16 + lane15;
            f32x4 a = acc[mt][nt];
            if (TR == 0) {
                C[(size_t)(rowb + 0) * N + col] = f2bf(a[0]);
                C[(size_t)(rowb + 1) * N + col] = f2bf(a[1]);
                C[(size_t)(rowb + 2) * N + col] = f2bf(a[2]);
                C[(size_t)(rowb + 3) * N + col] = f2bf(a[3]);
            } else {
                ushort4 o;
                o.x = f2bf(a[0]); o.y = f2bf(a[1]);
                o.z = f2bf(a[2]); o.w = f2bf(a[3]);
                *(ushort4*)(C + (size_t)col * M_PAD + rowb) = o;
            }
        }
    }
}

// Launch B: gemm1 tiles (blocks 0..781, row-major h1b) + CSR fill (rest,
// ATOMIC-FREE via precomputed ranks); both depend only on the scans.
__global__ __launch_bounds__(256) void fill_gemm1_kernel(
        const int* __restrict__ ei,
        const int* __restrict__ rl,
        const int* __restrict__ boff,
        const int* __restrict__ erank,
        int2* __restrict__ edge2,
        const float* __restrict__ dinv,
        const unsigned short* __restrict__ xb,
        const unsigned short* __restrict__ w1t,
        unsigned short* __restrict__ h1b) {
    __shared__ char As[8192];
    __shared__ char Bs[8192];
    int b = blockIdx.x;
    if (b < GEMM1_BLOCKS) {
        gemm_body<0>(xb, w1t, h1b, HID, b % 391, b / 391, As, Bs);
        return;
    }
    int e = (b - GEMM1_BLOCKS) * 256 + threadIdx.x;
    if (e >= N_EDGES) return;
    int s = ei[e];
    int d = ei[N_EDGES + e];
    int p = rp(rl, boff, d) + erank[e];
    float w = dinv[s] * dinv[d];
    edge2[p] = make_int2(s, __float_as_int(w));
}

// ---------------------------------------------------------------------------
// GCN aggregation conv1 (round-4 proven form, NO LDS -> full occupancy):
// wave/node, lane = 4ch uint2 gathers (512B/wave), 16-edge unroll, f32
// accumulate, ELU, packed bf16 out. Pad rows 50000..50047 zero-filled.
// ---------------------------------------------------------------------------
__global__ __launch_bounds__(256) void agg1_kernel(const unsigned short* __restrict__ h,
                                                   const float* __restrict__ bias,
                                                   const int* __restrict__ rl,
                                                   const int* __restrict__ boff,
                                                   const int2* __restrict__ edge2,
                                                   const float* __restrict__ invdeg,
                                                   unsigned short* __restrict__ out) {
    int node = blockIdx.x * 4 + (threadIdx.x >> 6);
    int lane = threadIdx.x & 63;
    if (node >= N_NODES) {
        if (node < M_PAD)
            ((ushort4*)out)[(size_t)node * 64 + lane] = make_ushort4(0, 0, 0, 0);
        return;
    }
    const uint2* h4 = (const uint2*)h;
    float id = invdeg[node];
    uint2 sv = h4[(size_t)node * 64 + lane];
    f32x4 acc = (f32x4){lo_f(sv.x) * id, hi_f(sv.x) * id,
                        lo_f(sv.y) * id, hi_f(sv.y) * id};
    int e0 = rp(rl, boff, node);
    int e1 = rp(rl, boff, node + 1);
    int e = e0;
    for (; e + 15 < e1; e += 16) {
        int2 ed[16];
        uint2 v[16];
#pragma unroll
        for (int j = 0; j < 16; j++) ed[j] = edge2[e + j];
#pragma unroll
        for (int j = 0; j < 16; j++) v[j] = h4[(size_t)ed[j].x * 64 + lane];
#pragma unroll
        for (int j = 0; j < 16; j++) {
            float w = __int_as_float(ed[j].y);
            f32x4 vf = (f32x4){lo_f(v[j].x), hi_f(v[j].x),
                               lo_f(v[j].y), hi_f(v[j].y)};
            acc += vf * w;
        }
    }
    for (; e + 7 < e1; e += 8) {
        int2 ed[8];
        uint2 v[8];
#pragma unroll
        for (int j = 0; j < 8; j++) ed[j] = edge2[e + j];
#pragma unroll
        for (int j = 0; j < 8; j++) v[j] = h4[(size_t)ed[j].x * 64 + lane];
#pragma unroll
        for (int j = 0; j < 8; j++) {
            float w = __int_as_float(ed[j].y);
            f32x4 vf = (f32x4){lo_f(v[j].x), hi_f(v[j].x),
                               lo_f(v[j].y), hi_f(v[j].y)};
            acc += vf * w;
        }
    }
    for (; e + 3 < e1; e += 4) {
        int2 ed[4];
        uint2 v[4];
#pragma unroll
        for (int j = 0; j < 4; j++) ed[j] = edge2[e + j];
#pragma unroll
        for (int j = 0; j < 4; j++) v[j] = h4[(size_t)ed[j].x * 64 + lane];
#pragma unroll
        for (int j = 0; j < 4; j++) {
            float w = __int_as_float(ed[j].y);
            f32x4 vf = (f32x4){lo_f(v[j].x), hi_f(v[j].x),
                               lo_f(v[j].y), hi_f(v[j].y)};
            acc += vf * w;
        }
    }
    for (; e < e1; e++) {
        int2 ed0 = edge2[e];
        float w0 = __int_as_float(ed0.y);
        uint2 v0 = h4[(size_t)ed0.x * 64 + lane];
        f32x4 vf = (f32x4){lo_f(v0.x), hi_f(v0.x), lo_f(v0.y), hi_f(v0.y)};
        acc += vf * w0;
    }
    float4 bb = ((const float4*)bias)[lane];
    acc[0] += bb.x; acc[1] += bb.y; acc[2] += bb.z; acc[3] += bb.w;
    acc[0] = acc[0] > 0.f ? acc[0] : expm1f(acc[0]);
    acc[1] = acc[1] > 0.f ? acc[1] : expm1f(acc[1]);
    acc[2] = acc[2] > 0.f ? acc[2] : expm1f(acc[2]);
    acc[3] = acc[3] > 0.f ? acc[3] : expm1f(acc[3]);
    ushort4 o;
    o.x = f2bf(acc[0]); o.y = f2bf(acc[1]); o.z = f2bf(acc[2]); o.w = f2bf(acc[3]);
    ((ushort4*)out)[(size_t)node * 64 + lane] = o;
}

// ---------------------------------------------------------------------------
// Merged launch (round-4 proven): gemm2 tiles (blocks 0..390, h2t transposed)
// + S-build (blocks 391..646): one block per (graph, column-quarter).
// S[g,s] = (sum_{edges s->d, d in g} w + [s in g]*invdeg[s]) / count(g).
// batch sorted => graph g's CSR edge range is contiguous => block scans it
// with LDS f32 atomics (50 KB slice), zero global atomics, streaming write.
// ---------------------------------------------------------------------------
__global__ __launch_bounds__(256) void gemm2_sbuild_kernel(
        const unsigned short* __restrict__ A,
        const unsigned short* __restrict__ Bt,
        unsigned short* __restrict__ C,
        const int2* __restrict__ edge2,
        const int* __restrict__ rl,
        const int* __restrict__ boff,
        const int* __restrict__ rstart,
        const float* __restrict__ invdeg,
        float* __restrict__ Sp) {
    __shared__ float srow[S_QUARTER];          // 50048 B; gemm uses first 16 KB
    int b = blockIdx.x;
    if (b < GEMM2_BLOCKS) {
        gemm_body<1>(A, Bt, C, OUT_CH, b, 0, (char*)srow, (char*)srow + 8192);
        return;
    }
    int sb = b - GEMM2_BLOCKS;
    int g = sb >> 2;
    int base = (sb & 3) * S_QUARTER;
    int t = threadIdx.x;
    for (int i = t; i < S_QUARTER; i += 256) srow[i] = 0.f;
    int n0 = rstart[g], n1 = rstart[g + 1];
    __syncthreads();
    int e0 = rp(rl, boff, n0);
    int e1 = rp(rl, boff, n1);
    for (int e = e0 + t; e < e1; e += 256) {
        int2 ed = edge2[e];
        unsigned int s = (unsigned int)(ed.x - base);
        if (s < S_QUARTER)
            atomicAdd(&srow[s], __int_as_float(ed.y));
    }
    __syncthreads();
    float ic = 1.0f / fmaxf((float)(n1 - n0), 1.0f);
    float* Sg = Sp + (size_t)g * SROW + base;
    for (int i = t; i < S_QUARTER; i += 256) {
        float v = srow[i];
        int col = base + i;
        if (col >= n0 && col < n1) v += invdeg[col];   // self-loop term
        Sg[i] = v * ic;
    }
}

// ---------------------------------------------------------------------------
// t2 = S @ h2 : [64 x 50048] x [50048 x 128] MFMA GEMM, K-split over 391
// blocks (Kc=128). A = S (f32, split in-kernel into bf16 hi+lo limbs, two
// MFMAs sharing the B fragment -> ~2^-17 weight error, f32 accumulate).
// B = h2t (k-contiguous rows). Pure streaming: no gathers, no LDS.
// ---------------------------------------------------------------------------
__global__ __launch_bounds__(256) void t2_kernel(const float* __restrict__ Sp,
                                                 const unsigned short* __restrict__ h2t,
                                                 float* __restrict__ part) {
    int b = blockIdx.x;
    int k0 = b * T2_KC;
    int tid = threadIdx.x;
    int lane = tid & 63, wave = tid >> 6;
    int lane15 = lane & 15, quad = lane >> 4;
    int cb = wave << 5;                    // 32 channels per wave
    f32x4 acc[4][2];
#pragma unroll
    for (int m = 0; m < 4; m++) {
        acc[m][0] = (f32x4){0.f, 0.f, 0.f, 0.f};
        acc[m][1] = (f32x4){0.f, 0.f, 0.f, 0.f};
    }
    const unsigned short* hr0 = h2t + (size_t)(cb + lane15) * M_PAD;
    const unsigned short* hr1 = h2t + (size_t)(cb + 16 + lane15) * M_PAD;
#pragma unroll
    for (int ks = 0; ks < T2_KC / 32; ks++) {
        int k = k0 + ks * 32 + quad * 8;
        bf16x8 b0 = *(const bf16x8*)(hr0 + k);
        bf16x8 b1 = *(const bf16x8*)(hr1 + k);
#pragma unroll
        for (int m = 0; m < 4; m++) {
            const float* ap = Sp + (size_t)(m * 16 + lane15) * SROW + k;
            f32x4 v0 = *(const f32x4*)ap;
            f32x4 v1 = *(const f32x4*)(ap + 4);
            u16x8 hu, lu;
#pragma unroll
            for (int j = 0; j < 4; j++) {
                unsigned int e0 = __float_as_uint(v0[j]);
                hu[j] = (unsigned short)(e0 >> 16);                       // trunc hi
                lu[j] = f2bf(v0[j] - __uint_as_float(e0 & 0xFFFF0000u));  // residual
                unsigned int e1 = __float_as_uint(v1[j]);
                hu[j + 4] = (unsigned short)(e1 >> 16);
                lu[j + 4] = f2bf(v1[j] - __uint_as_float(e1 & 0xFFFF0000u));
            }
            bf16x8 ah = __builtin_bit_cast(bf16x8, hu);
            bf16x8 al = __builtin_bit_cast(bf16x8, lu);
            acc[m][0] = __builtin_amdgcn_mfma_f32_16x16x32_bf16(ah, b0, acc[m][0], 0, 0, 0);
            acc[m][0] = __builtin_amdgcn_mfma_f32_16x16x32_bf16(al, b0, acc[m][0], 0, 0, 0);
            acc[m][1] = __builtin_amdgcn_mfma_f32_16x16x32_bf16(ah, b1, acc[m][1], 0, 0, 0);
            acc[m][1] = __builtin_amdgcn_mfma_f32_16x16x32_bf16(al, b1, acc[m][1], 0, 0, 0);
        }
    }
    float* pb = part + (size_t)b * (N_GRAPHS * OUT_CH);
#pragma unroll
    for (int m = 0; m < 4; m++) {
        int g0 = m * 16 + quad * 4;
#pragma unroll
        for (int nt = 0; nt < 2; nt++) {
            int c = cb + nt * 16 + lane15;
            f32x4 a = acc[m][nt];
#pragma unroll
            for (int j = 0; j < 4; j++)
                pb[(g0 + j) * OUT_CH + c] = a[j];
        }
    }
}

// reduce partials over 391 blocks, add bias, empty-graph guard, write out.
__global__ __launch_bounds__(256) void t2red_kernel(const float* __restrict__ part,
                                                    const float* __restrict__ b2,
                                                    const int* __restrict__ rstart,
                                                    float* __restrict__ out) {
    __shared__ float red[4][64];
    int tid = threadIdx.x;
    int q = tid >> 6, l = tid & 63;
    int o = blockIdx.x * 64 + l;
    float s = 0.f;
    for (int i = q; i < T2_BLOCKS; i += 4)
        s += part[(size_t)i * (N_GRAPHS * OUT_CH) + o];
    red[q][l] = s;
    __syncthreads();
    if (tid < 64) {
        float tot = red[0][l] + red[1][l] + red[2][l] + red[3][l];
        int g = o >> 7, c = o & 127;
        out[o] = (rstart[g + 1] > rstart[g]) ? tot + b2[c] : 0.f;
    }
}

// ---------------------------------------------------------------------------
extern "C" void kernel_launch(void* const* d_in, const int* in_sizes, int n_in,
                              void* d_out, int out_size, void* d_ws, size_t ws_size,
                              hipStream_t stream) {
    const float* x  = (const float*)d_in[0];
    const float* W1 = (const float*)d_in[1];
    const float* b1 = (const float*)d_in[2];
    const float* W2 = (const float*)d_in[3];
    const float* b2 = (const float*)d_in[4];
    const int*   ei = (const int*)d_in[5];
    const int*   batch = (const int*)d_in[6];
    float* out = (float*)d_out;

    // workspace layout (16B-aligned by construction)
    unsigned short* xb  = (unsigned short*)d_ws;                 // M_PAD*256 bf16
    unsigned short* h1b = xb  + (size_t)M_PAD * IN_CH;           // M_PAD*256 bf16
    unsigned short* hBb = h1b + (size_t)M_PAD * HID;             // M_PAD*256 bf16
    unsigned short* h2t = hBb + (size_t)M_PAD * HID;             // 128*M_PAD bf16 (transposed)
    unsigned short* w1t = h2t + (size_t)OUT_CH * M_PAD;          // 256*256
    unsigned short* w2t = w1t + HID * IN_CH;                     // 128*256
    float* dinv   = (float*)(w2t + OUT_CH * HID);                // 50000
    float* invdeg = dinv + N_NODES;                              // 50000
    int*   rl     = (int*)(invdeg + N_NODES);                    // 50001 (pad 50016)
    int2*  edge2  = (int2*)(rl + 50016);                         // 800000 int2
    int*   cnt    = (int*)(edge2 + N_EDGES);                     // 50000 (memset)
    int*   erank  = cnt + N_NODES;                               // 800000 (edge ranks)
    int*   blocksum = erank + N_EDGES;                           // 256
    int*   blockoff = blocksum + 256;                            // 256
    int*   rstart   = blockoff + 256;                            // 65 (pad 80)
    float* Sp     = (float*)(rstart + 80);                       // 64*50048 f32
    float* part   = (float*)xb;   // t2 partials alias xb (dead after gemm1)

    hipMemsetAsync(cnt, 0, (size_t)N_NODES * 4, stream);

    // A: histogram+rank + x convert + W convert (independent, one launch)
    count_cvtx_cvtw_kernel<<<COUNT_BLOCKS + CVTX_BLOCKS + CVTW_BLOCKS, 256, 0, stream>>>(
        ei, cnt, erank, x, xb, W1, W2, w1t, w2t);
    // scan phase (detects graph boundaries)
    scan_a_kernel<<<SCAN_BLOCKS, 256, 0, stream>>>(cnt, rl, blocksum, dinv, invdeg,
                                                   batch, rstart);
    // blockoff scan (single block)
    scanb1_kernel<<<1, 256, 0, stream>>>(blocksum, blockoff);
    // B: gemm1 tiles + atomic-free CSR fill (one launch)
    fill_gemm1_kernel<<<GEMM1_BLOCKS + COUNT_BLOCKS, 256, 0, stream>>>(
        ei, rl, blockoff, erank, edge2, dinv, xb, w1t, h1b);
    // conv1 aggregate (+ELU), pure round-4 form (no LDS)
    agg1_kernel<<<M_PAD / 4, 256, 0, stream>>>(h1b, b1, rl, blockoff,
                                               edge2, invdeg, hBb);
    // conv2 GEMM (h2t transposed out) + S-build (LDS, no global atomics)
    gemm2_sbuild_kernel<<<GEMM2_BLOCKS + SBUILD_BLOCKS, 256, 0, stream>>>(
        hBb, w2t, h2t, edge2, rl, blockoff, rstart, invdeg, Sp);
    // fused agg2+pool+mean as dense streaming GEMM out = S @ h2 + b2
    t2_kernel<<<T2_BLOCKS, 256, 0, stream>>>(Sp, h2t, part);
    t2red_kernel<<<RED_BLOCKS, 256, 0, stream>>>(part, b2, rstart, out);
}